// Round 1
// baseline (6225.710 us; speedup 1.0000x reference)
//
#include <hip/hip_runtime.h>
#include <math.h>

#define TT 1024
#define BB 4
#define CH 256
#define NH 4
#define HDIM 64
#define DFFN 1024
#define KW 31
#define NL 2
#define TB (TT*BB)
#define EPSV 1e-5f

// ---------------- LayerNorm: one block per row of 256 ----------------
__global__ __launch_bounds__(256)
void ln_kernel(const float* __restrict__ X, const float* __restrict__ G,
               const float* __restrict__ Bt, float* __restrict__ Y)
{
    int row = blockIdx.x;
    int c = threadIdx.x;
    float v = X[(size_t)row*CH + c];
    float s = v, s2 = v*v;
    #pragma unroll
    for (int off = 32; off >= 1; off >>= 1) {
        s  += __shfl_xor(s, off);
        s2 += __shfl_xor(s2, off);
    }
    __shared__ float rs[4], rs2[4];
    if ((c & 63) == 0) { rs[c>>6] = s; rs2[c>>6] = s2; }
    __syncthreads();
    s  = rs[0]+rs[1]+rs[2]+rs[3];
    s2 = rs2[0]+rs2[1]+rs2[2]+rs2[3];
    float mean = s * (1.0f/CH);
    float var  = s2 * (1.0f/CH) - mean*mean;
    float inv  = rsqrtf(var + EPSV);
    Y[(size_t)row*CH + c] = (v - mean) * inv * G[c] + Bt[c];
}

// ---------------- Generic GEMM: C[m,n] = R + scale*act(sum_k A[m,k]*B[n,k] + biasM[m] + biasN[n])
// A row-contiguous in k (stride lda), B row-contiguous in k (stride ldb).
// C addressed as m*ldcm + n*ldcn (residual same layout). blockIdx.z batches via sA/sB/sC.
template<int ACT>
__global__ __launch_bounds__(256)
void gemm_kernel(const float* __restrict__ A, int lda, long sA,
                 const float* __restrict__ Bm, int ldb, long sB,
                 float* __restrict__ Cm, long ldcm, long ldcn, long sC,
                 const float* __restrict__ biasM, const float* __restrict__ biasN,
                 const float* __restrict__ Rm, float scale,
                 int M, int N, int Kd)
{
    __shared__ float As[16][64];
    __shared__ float Bs[16][64];
    int bz = blockIdx.z;
    A  += (long)bz * sA;
    Bm += (long)bz * sB;
    Cm += (long)bz * sC;
    const float* Rp = Rm ? (Rm + (long)bz * sC) : nullptr;
    int m0 = blockIdx.y * 64;
    int n0 = blockIdx.x * 64;
    int tid = threadIdx.x;
    int tx = tid & 15, ty = tid >> 4;
    int lm = tid >> 2;          // 0..63
    int lk = (tid & 3) << 2;    // 0,4,8,12
    float acc[4][4] = {{0.f}};
    for (int k0 = 0; k0 < Kd; k0 += 16) {
        float4 av = {0,0,0,0}, bv = {0,0,0,0};
        int gm = m0 + lm;
        if (gm < M) av = *(const float4*)(A  + (long)gm*lda + k0 + lk);
        int gn = n0 + lm;
        if (gn < N) bv = *(const float4*)(Bm + (long)gn*ldb + k0 + lk);
        As[lk+0][lm]=av.x; As[lk+1][lm]=av.y; As[lk+2][lm]=av.z; As[lk+3][lm]=av.w;
        Bs[lk+0][lm]=bv.x; Bs[lk+1][lm]=bv.y; Bs[lk+2][lm]=bv.z; Bs[lk+3][lm]=bv.w;
        __syncthreads();
        #pragma unroll
        for (int k = 0; k < 16; ++k) {
            float ar[4], br[4];
            #pragma unroll
            for (int i = 0; i < 4; ++i) ar[i] = As[k][ty + 16*i];
            #pragma unroll
            for (int j = 0; j < 4; ++j) br[j] = Bs[k][tx + 16*j];
            #pragma unroll
            for (int i = 0; i < 4; ++i)
                #pragma unroll
                for (int j = 0; j < 4; ++j)
                    acc[i][j] += ar[i]*br[j];
        }
        __syncthreads();
    }
    #pragma unroll
    for (int i = 0; i < 4; ++i) {
        int m = m0 + ty + 16*i;
        if (m >= M) continue;
        float bm = biasM ? biasM[m] : 0.f;
        #pragma unroll
        for (int j = 0; j < 4; ++j) {
            int n = n0 + tx + 16*j;
            if (n >= N) continue;
            float v = acc[i][j] + bm + (biasN ? biasN[n] : 0.f);
            if (ACT == 1) v = v / (1.f + __expf(-v));   // swish
            v *= scale;
            long ci = (long)m*ldcm + (long)n*ldcn;
            if (Rp) v += Rp[ci];
            Cm[ci] = v;
        }
    }
}

// ---------------- qkv -> scaled q+bu, q+bv, k, v in (B,H,T,HD) ----------------
__global__ __launch_bounds__(256)
void prep_kernel(const float* __restrict__ QKV, const float* __restrict__ BU,
                 const float* __restrict__ BV,
                 float* __restrict__ qu, float* __restrict__ qv,
                 float* __restrict__ kk, float* __restrict__ vv)
{
    int idx = blockIdx.x*256 + threadIdx.x;      // B*H*T*HD = 2^20
    int d = idx & 63;
    int t = (idx >> 6)  & (TT-1);
    int h = (idx >> 16) & (NH-1);
    int b = idx >> 18;
    size_t src = ((size_t)(t*BB + b))*(3*CH) + h*HDIM + d;
    const float scaling = 0.125f;                // HD^-0.5
    float q = QKV[src] * scaling;
    qu[idx] = q + BU[h*HDIM + d];
    qv[idx] = q + BV[h*HDIM + d];
    kk[idx] = QKV[src + CH];
    vv[idx] = QKV[src + 2*CH];
}

// ---------------- attention: one block per (b,h,t) row ----------------
// scores[j] = qu·k[j] + qv·p[1023-t+j]  (fused rel_shift), softmax, o = w@v
__global__ __launch_bounds__(256)
void attn_kernel(const float* __restrict__ QU, const float* __restrict__ QV,
                 const float* __restrict__ KK, const float* __restrict__ VV,
                 const float* __restrict__ P,   // (2T-1, CH) projected pos
                 float* __restrict__ O)         // token-major (T*B, CH)
{
    int t = blockIdx.x, h = blockIdx.y, b = blockIdx.z;
    int tid = threadIdx.x;
    __shared__ float qu[HDIM], qv[HDIM];
    __shared__ float sc[TT];
    __shared__ float red[8];
    __shared__ float opart[256];
    size_t bh = ((size_t)b*NH + h) * TT;
    if (tid < 64)       qu[tid]    = QU[(bh + t)*HDIM + tid];
    else if (tid < 128) qv[tid-64] = QV[(bh + t)*HDIM + (tid-64)];
    __syncthreads();

    const float* Kbase = KK + bh*HDIM;
    const float* Pbase = P + h*HDIM;
    int nbase = (TT-1) - t;
    #pragma unroll
    for (int r = 0; r < 4; ++r) {
        int j = tid + 256*r;
        const float4* krow = (const float4*)(Kbase + (size_t)j*HDIM);
        const float4* prow = (const float4*)(Pbase + (size_t)(nbase + j)*CH);
        float ac = 0.f, bd = 0.f;
        #pragma unroll
        for (int q4 = 0; q4 < 16; ++q4) {
            float4 kvv = krow[q4];
            float4 pvv = prow[q4];
            float4 quv = *(const float4*)(qu + q4*4);
            float4 qvv = *(const float4*)(qv + q4*4);
            ac += quv.x*kvv.x + quv.y*kvv.y + quv.z*kvv.z + quv.w*kvv.w;
            bd += qvv.x*pvv.x + qvv.y*pvv.y + qvv.z*pvv.z + qvv.w*pvv.w;
        }
        sc[j] = ac + bd;
    }
    __syncthreads();

    float mx = -1e30f;
    #pragma unroll
    for (int r = 0; r < 4; ++r) mx = fmaxf(mx, sc[tid + 256*r]);
    #pragma unroll
    for (int off = 32; off >= 1; off >>= 1) mx = fmaxf(mx, __shfl_xor(mx, off));
    if ((tid & 63) == 0) red[tid>>6] = mx;
    __syncthreads();
    mx = fmaxf(fmaxf(red[0],red[1]), fmaxf(red[2],red[3]));

    float sum = 0.f;
    #pragma unroll
    for (int r = 0; r < 4; ++r) {
        int j = tid + 256*r;
        float e = __expf(sc[j] - mx);
        sc[j] = e;
        sum += e;
    }
    #pragma unroll
    for (int off = 32; off >= 1; off >>= 1) sum += __shfl_xor(sum, off);
    if ((tid & 63) == 0) red[4 + (tid>>6)] = sum;
    __syncthreads();
    float denom = red[4]+red[5]+red[6]+red[7];

    int d = tid & 63;
    int chunk = tid >> 6;
    const float* Vb = VV + bh*HDIM;
    float part = 0.f;
    for (int j = chunk*256; j < (chunk+1)*256; ++j)
        part += sc[j] * Vb[(size_t)j*HDIM + d];
    opart[tid] = part;
    __syncthreads();
    if (tid < 64) {
        float o = (opart[tid] + opart[64+tid] + opart[128+tid] + opart[192+tid]) / denom;
        O[((size_t)t*BB + b)*CH + h*HDIM + tid] = o;
    }
}

// ---------------- GLU: a * sigmoid(g) over (B,C,T) halves of (B,2C,T) ----------------
__global__ __launch_bounds__(256)
void glu_kernel(const float* __restrict__ In, float* __restrict__ Out)
{
    size_t idx = (size_t)blockIdx.x*256 + threadIdx.x;   // B*C*T
    size_t b = idx >> 18;                                // C*T = 2^18
    size_t r = idx & (((size_t)1<<18)-1);
    const float* base = In + b*(2*CH*TT);
    float a = base[r];
    float g = base[CH*TT + r];
    Out[idx] = a / (1.f + __expf(-g));
}

// ---------------- depthwise conv(K=31) + bias + BN + swish, write token-major ----------------
__global__ __launch_bounds__(256)
void dwconv_kernel(const float* __restrict__ In,   // (B,C,T)
                   const float* __restrict__ W,    // (C,K)
                   const float* __restrict__ CB,
                   const float* __restrict__ BNG, const float* __restrict__ BNB,
                   const float* __restrict__ BNM, const float* __restrict__ BNV,
                   float* __restrict__ Out)        // (T*B, C)
{
    int c = blockIdx.x, b = blockIdx.y;
    __shared__ float row[TT + KW - 1];
    __shared__ float wv[KW];
    int tid = threadIdx.x;
    const float* base = In + ((size_t)b*CH + c)*TT;
    for (int i = tid; i < TT + KW - 1; i += 256) {
        int tp = i - (KW-1)/2;
        row[i] = (tp >= 0 && tp < TT) ? base[tp] : 0.f;
    }
    if (tid < KW) wv[tid] = W[c*KW + tid];
    float bias = CB[c];
    float scl  = rsqrtf(BNV[c] + EPSV) * BNG[c];
    float sh   = BNB[c];
    float mn   = BNM[c];
    __syncthreads();
    #pragma unroll
    for (int r = 0; r < 4; ++r) {
        int t = tid + 256*r;
        float acc = 0.f;
        #pragma unroll
        for (int k = 0; k < KW; ++k) acc += row[t + k] * wv[k];
        float v = (acc + bias - mn) * scl + sh;
        v = v / (1.f + __expf(-v));
        Out[((size_t)t*BB + b)*CH + c] = v;
    }
}

extern "C" void kernel_launch(void* const* d_in, const int* in_sizes, int n_in,
                              void* d_out, int out_size, void* d_ws, size_t ws_size,
                              hipStream_t stream)
{
    const float* x_in    = (const float*)d_in[0];
    const float* pos_emb = (const float*)d_in[1];
    const float* ffm_w1  = (const float*)d_in[2];
    const float* ffm_b1  = (const float*)d_in[3];
    const float* ffm_w2  = (const float*)d_in[4];
    const float* ffm_b2  = (const float*)d_in[5];
    const float* ff_w1   = (const float*)d_in[6];
    const float* ff_b1   = (const float*)d_in[7];
    const float* ff_w2   = (const float*)d_in[8];
    const float* ff_b2   = (const float*)d_in[9];
    const float* in_w    = (const float*)d_in[10];
    const float* in_b    = (const float*)d_in[11];
    const float* out_w   = (const float*)d_in[12];
    const float* out_b   = (const float*)d_in[13];
    const float* pos_w   = (const float*)d_in[14];
    const float* bias_u  = (const float*)d_in[15];
    const float* bias_v  = (const float*)d_in[16];
    const float* pw1_w   = (const float*)d_in[17];
    const float* pw1_b   = (const float*)d_in[18];
    const float* dw_w    = (const float*)d_in[19];
    const float* dw_b    = (const float*)d_in[20];
    const float* bn_g    = (const float*)d_in[21];
    const float* bn_b    = (const float*)d_in[22];
    const float* bn_m    = (const float*)d_in[23];
    const float* bn_v    = (const float*)d_in[24];
    const float* pw2_w   = (const float*)d_in[25];
    const float* pw2_b   = (const float*)d_in[26];
    const float* ln_g    = (const float*)d_in[27];
    const float* ln_b    = (const float*)d_in[28];

    float* ws = (float*)d_ws;
    float* xbuf = ws;   ws += (size_t)TB*CH;
    float* ybuf = ws;   ws += (size_t)TB*CH;
    float* hbuf = ws;   ws += (size_t)TB*DFFN;
    float* qu   = ws;   ws += (size_t)BB*NH*TT*HDIM;
    float* qv   = ws;   ws += (size_t)BB*NH*TT*HDIM;
    float* kbuf = ws;   ws += (size_t)BB*NH*TT*HDIM;
    float* vbuf = ws;   ws += (size_t)BB*NH*TT*HDIM;
    float* pbuf = ws;   ws += (size_t)2*TT*CH;
    float* c1   = ws;   ws += (size_t)BB*2*CH*TT;
    float* abuf = ws;   ws += (size_t)TB*CH;
    float* c2   = ws;   ws += (size_t)BB*CH*TT;
    size_t need_bytes = (size_t)(ws - (float*)d_ws) * sizeof(float);
    if (ws_size < need_bytes) return;   // avoid corruption; bench will flag mismatch

    const float* cur = x_in;
    for (int i = 0; i < NL; ++i) {
        const float* lng = ln_g + (size_t)i*5*CH;
        const float* lnb = ln_b + (size_t)i*5*CH;

        // ---- macaron FFN ----
        ln_kernel<<<TB, 256, 0, stream>>>(cur, lng + 0*CH, lnb + 0*CH, ybuf);
        gemm_kernel<1><<<dim3(DFFN/64, TB/64, 1), 256, 0, stream>>>(
            ybuf, CH, 0, ffm_w1 + (size_t)i*DFFN*CH, CH, 0,
            hbuf, DFFN, 1, 0, nullptr, ffm_b1 + (size_t)i*DFFN, nullptr, 1.f,
            TB, DFFN, CH);
        gemm_kernel<0><<<dim3(CH/64, TB/64, 1), 256, 0, stream>>>(
            hbuf, DFFN, 0, ffm_w2 + (size_t)i*CH*DFFN, DFFN, 0,
            xbuf, CH, 1, 0, nullptr, ffm_b2 + (size_t)i*CH, cur, 0.5f,
            TB, CH, DFFN);
        cur = xbuf;

        // ---- rel-pos attention ----
        ln_kernel<<<TB, 256, 0, stream>>>(cur, lng + 1*CH, lnb + 1*CH, ybuf);
        gemm_kernel<0><<<dim3(3*CH/64, TB/64, 1), 256, 0, stream>>>(
            ybuf, CH, 0, in_w + (size_t)i*3*CH*CH, CH, 0,
            hbuf, 3*CH, 1, 0, nullptr, in_b + (size_t)i*3*CH, nullptr, 1.f,
            TB, 3*CH, CH);
        gemm_kernel<0><<<dim3(CH/64, (2*TT-1+63)/64, 1), 256, 0, stream>>>(
            pos_emb, CH, 0, pos_w + (size_t)i*CH*CH, CH, 0,
            pbuf, CH, 1, 0, nullptr, nullptr, nullptr, 1.f,
            2*TT-1, CH, CH);
        prep_kernel<<<(BB*NH*TT*HDIM)/256, 256, 0, stream>>>(
            hbuf, bias_u + (size_t)i*NH*HDIM, bias_v + (size_t)i*NH*HDIM,
            qu, qv, kbuf, vbuf);
        attn_kernel<<<dim3(TT, NH, BB), 256, 0, stream>>>(qu, qv, kbuf, vbuf, pbuf, abuf);
        gemm_kernel<0><<<dim3(CH/64, TB/64, 1), 256, 0, stream>>>(
            abuf, CH, 0, out_w + (size_t)i*CH*CH, CH, 0,
            xbuf, CH, 1, 0, nullptr, out_b + (size_t)i*CH, cur, 1.f,
            TB, CH, CH);

        // ---- conv module ----
        ln_kernel<<<TB, 256, 0, stream>>>(cur, lng + 2*CH, lnb + 2*CH, ybuf);
        gemm_kernel<0><<<dim3(TT/64, (2*CH)/64, BB), 256, 0, stream>>>(
            pw1_w + (size_t)i*2*CH*CH, CH, 0, ybuf, BB*CH, CH,
            c1, TT, 1, (long)2*CH*TT, pw1_b + (size_t)i*2*CH, nullptr, nullptr, 1.f,
            2*CH, TT, CH);
        glu_kernel<<<(BB*CH*TT)/256, 256, 0, stream>>>(c1, c2);
        dwconv_kernel<<<dim3(CH, BB), 256, 0, stream>>>(
            c2, dw_w + (size_t)i*CH*KW, dw_b + (size_t)i*CH,
            bn_g + (size_t)i*CH, bn_b + (size_t)i*CH,
            bn_m + (size_t)i*CH, bn_v + (size_t)i*CH, abuf);
        gemm_kernel<0><<<dim3(CH/64, TB/64, 1), 256, 0, stream>>>(
            abuf, CH, 0, pw2_w + (size_t)i*CH*CH, CH, 0,
            xbuf, CH, 1, 0, nullptr, pw2_b + (size_t)i*CH, cur, 1.f,
            TB, CH, CH);

        // ---- second FFN ----
        ln_kernel<<<TB, 256, 0, stream>>>(cur, lng + 3*CH, lnb + 3*CH, ybuf);
        gemm_kernel<1><<<dim3(DFFN/64, TB/64, 1), 256, 0, stream>>>(
            ybuf, CH, 0, ff_w1 + (size_t)i*DFFN*CH, CH, 0,
            hbuf, DFFN, 1, 0, nullptr, ff_b1 + (size_t)i*DFFN, nullptr, 1.f,
            TB, DFFN, CH);
        gemm_kernel<0><<<dim3(CH/64, TB/64, 1), 256, 0, stream>>>(
            hbuf, DFFN, 0, ff_w2 + (size_t)i*CH*DFFN, DFFN, 0,
            xbuf, CH, 1, 0, nullptr, ff_b2 + (size_t)i*CH, cur, 0.5f,
            TB, CH, DFFN);

        // ---- final LN of the layer ----
        float* lnout = (i == NL-1) ? (float*)d_out : xbuf;
        ln_kernel<<<TB, 256, 0, stream>>>(xbuf, lng + 4*CH, lnb + 4*CH, lnout);
        cur = xbuf;
    }
}

// Round 2
// 1152.350 us; speedup vs baseline: 5.4026x; 5.4026x over previous
//
#include <hip/hip_runtime.h>
#include <math.h>

#define TT 1024
#define BB 4
#define CH 256
#define NH 4
#define HDIM 64
#define DFFN 1024
#define KW 31
#define NL 2
#define TB (TT*BB)
#define EPSV 1e-5f

typedef __attribute__((ext_vector_type(8))) short short8;
typedef __attribute__((ext_vector_type(4))) float f32x4;

__device__ __forceinline__ short f2bf(float f){
    union { float f; unsigned u; } x; x.f = f;
    unsigned r = x.u + 0x7fffu + ((x.u >> 16) & 1u);
    return (short)(r >> 16);
}

// ---------------- LayerNorm: one block per row of 256 ----------------
__global__ __launch_bounds__(256)
void ln_kernel(const float* __restrict__ X, const float* __restrict__ G,
               const float* __restrict__ Bt, float* __restrict__ Y)
{
    int row = blockIdx.x;
    int c = threadIdx.x;
    float v = X[(size_t)row*CH + c];
    float s = v, s2 = v*v;
    #pragma unroll
    for (int off = 32; off >= 1; off >>= 1) {
        s  += __shfl_xor(s, off);
        s2 += __shfl_xor(s2, off);
    }
    __shared__ float rs[4], rs2[4];
    if ((c & 63) == 0) { rs[c>>6] = s; rs2[c>>6] = s2; }
    __syncthreads();
    s  = rs[0]+rs[1]+rs[2]+rs[3];
    s2 = rs2[0]+rs2[1]+rs2[2]+rs2[3];
    float mean = s * (1.0f/CH);
    float var  = s2 * (1.0f/CH) - mean*mean;
    float inv  = rsqrtf(var + EPSV);
    Y[(size_t)row*CH + c] = (v - mean) * inv * G[c] + Bt[c];
}

// ---------------- Generic GEMM (fp32, VALU) ----------------
template<int ACT>
__global__ __launch_bounds__(256)
void gemm_kernel(const float* __restrict__ A, int lda, long sA,
                 const float* __restrict__ Bm, int ldb, long sB,
                 float* __restrict__ Cm, long ldcm, long ldcn, long sC,
                 const float* __restrict__ biasM, const float* __restrict__ biasN,
                 const float* __restrict__ Rm, float scale,
                 int M, int N, int Kd)
{
    __shared__ float As[16][64];
    __shared__ float Bs[16][64];
    int bz = blockIdx.z;
    A  += (long)bz * sA;
    Bm += (long)bz * sB;
    Cm += (long)bz * sC;
    const float* Rp = Rm ? (Rm + (long)bz * sC) : nullptr;
    int m0 = blockIdx.y * 64;
    int n0 = blockIdx.x * 64;
    int tid = threadIdx.x;
    int tx = tid & 15, ty = tid >> 4;
    int lm = tid >> 2;
    int lk = (tid & 3) << 2;
    float acc[4][4] = {{0.f}};
    for (int k0 = 0; k0 < Kd; k0 += 16) {
        float4 av = {0,0,0,0}, bv = {0,0,0,0};
        int gm = m0 + lm;
        if (gm < M) av = *(const float4*)(A  + (long)gm*lda + k0 + lk);
        int gn = n0 + lm;
        if (gn < N) bv = *(const float4*)(Bm + (long)gn*ldb + k0 + lk);
        As[lk+0][lm]=av.x; As[lk+1][lm]=av.y; As[lk+2][lm]=av.z; As[lk+3][lm]=av.w;
        Bs[lk+0][lm]=bv.x; Bs[lk+1][lm]=bv.y; Bs[lk+2][lm]=bv.z; Bs[lk+3][lm]=bv.w;
        __syncthreads();
        #pragma unroll
        for (int k = 0; k < 16; ++k) {
            float ar[4], br[4];
            #pragma unroll
            for (int i = 0; i < 4; ++i) ar[i] = As[k][ty + 16*i];
            #pragma unroll
            for (int j = 0; j < 4; ++j) br[j] = Bs[k][tx + 16*j];
            #pragma unroll
            for (int i = 0; i < 4; ++i)
                #pragma unroll
                for (int j = 0; j < 4; ++j)
                    acc[i][j] += ar[i]*br[j];
        }
        __syncthreads();
    }
    #pragma unroll
    for (int i = 0; i < 4; ++i) {
        int m = m0 + ty + 16*i;
        if (m >= M) continue;
        float bm = biasM ? biasM[m] : 0.f;
        #pragma unroll
        for (int j = 0; j < 4; ++j) {
            int n = n0 + tx + 16*j;
            if (n >= N) continue;
            float v = acc[i][j] + bm + (biasN ? biasN[n] : 0.f);
            if (ACT == 1) v = v / (1.f + __expf(-v));
            v *= scale;
            long ci = (long)m*ldcm + (long)n*ldcn;
            if (Rp) v += Rp[ci];
            Cm[ci] = v;
        }
    }
}

// ---------------- qkv -> bf16 qu, qv, k (bh,t,d) and v transposed (bh,d,t) ----------------
__global__ __launch_bounds__(256)
void prep_kernel(const float* __restrict__ QKV, const float* __restrict__ BU,
                 const float* __restrict__ BV,
                 short* __restrict__ qub, short* __restrict__ qvb,
                 short* __restrict__ kb, short* __restrict__ vtb)
{
    int idx = blockIdx.x*256 + threadIdx.x;      // ((b*NH+h)*TT + t)*64 + d
    int d = idx & 63;
    int t = (idx >> 6)  & (TT-1);
    int h = (idx >> 16) & (NH-1);
    int b = idx >> 18;
    size_t src = ((size_t)(t*BB + b))*(3*CH) + h*HDIM + d;
    float q = QKV[src] * 0.125f;                 // HD^-0.5
    qub[idx] = f2bf(q + BU[h*HDIM + d]);
    qvb[idx] = f2bf(q + BV[h*HDIM + d]);
    kb[idx]  = f2bf(QKV[src + CH]);
    int bh = b*NH + h;
    vtb[((size_t)bh*HDIM + d)*TT + t] = f2bf(QKV[src + 2*CH]);
}

// ---------------- projected pos -> bf16 (h, n, d), row 2047 zeroed ----------------
__global__ __launch_bounds__(256)
void pt_kernel(const float* __restrict__ P, short* __restrict__ pbf)
{
    int idx = blockIdx.x*256 + threadIdx.x;      // ((h*2048)+n)*64 + d
    int d = idx & 63;
    int n = (idx >> 6) & 2047;
    float v = (n < 2*TT-1) ? P[(size_t)n*CH + (idx>>17)*HDIM + d] : 0.f;
    pbf[idx] = f2bf(v);
}

// ---------------- MFMA flash attention with fused rel_shift ----------------
// grid (T/64, H, B), 256 threads = 4 waves; wave w owns q rows [t0+16w, +16)
__global__ __launch_bounds__(256)
void attn_mfma_kernel(const short* __restrict__ qub, const short* __restrict__ qvb,
                      const short* __restrict__ kb, const short* __restrict__ vtb,
                      const short* __restrict__ pbf, float* __restrict__ O)
{
    const int t0 = blockIdx.x * 64;
    const int h  = blockIdx.y, b = blockIdx.z;
    const int bh = b*NH + h;
    const int tid = threadIdx.x;
    const int w = tid >> 6, lane = tid & 63;
    const int g = lane >> 4, c = lane & 15;

    __shared__ short Kl[64][88];     // [j][d]
    __shared__ short Vl[64][88];     // [d][j]  (V transposed)
    __shared__ short Pl[128][88];    // [m][d]  pos rows nb..nb+127
    __shared__ float BDs[4][16][84]; // per-wave BD strip
    __shared__ short Pa[4][16][88];  // per-wave P (bf16) for PV A-operand

    short8 qa[2], qv[2];
    {
        const short* qr = qub + ((size_t)bh*TT + t0 + 16*w + c)*HDIM;
        const short* vr = qvb + ((size_t)bh*TT + t0 + 16*w + c)*HDIM;
        qa[0] = *(const short8*)(qr + 8*g);
        qa[1] = *(const short8*)(qr + 32 + 8*g);
        qv[0] = *(const short8*)(vr + 8*g);
        qv[1] = *(const short8*)(vr + 32 + 8*g);
    }

    f32x4 acc_o[4] = {};
    float m_run[4], l_run[4];
    #pragma unroll
    for (int r = 0; r < 4; ++r){ m_run[r] = -1e30f; l_run[r] = 0.f; }

    for (int jt = 0; jt < 16; ++jt) {
        const int j0 = jt*64;
        const int nb = 960 - t0 + j0;            // pos-tile base row
        __syncthreads();
        {   // stage K (8KB contiguous)
            const short* src = kb + ((size_t)bh*TT + j0)*HDIM;
            #pragma unroll
            for (int p = 0; p < 2; ++p) {
                int ci = tid + p*256;
                *(short8*)&Kl[ci>>3][(ci&7)*8] = *(const short8*)(src + ci*8);
            }
            // stage Vt (64 rows of 128B)
            #pragma unroll
            for (int p = 0; p < 2; ++p) {
                int ci = tid + p*256;
                *(short8*)&Vl[ci>>3][(ci&7)*8] =
                    *(const short8*)(vtb + ((size_t)bh*HDIM + (ci>>3))*TT + j0 + (ci&7)*8);
            }
            // stage P (16KB contiguous)
            const short* ps = pbf + ((size_t)h*2048 + nb)*HDIM;
            #pragma unroll
            for (int p = 0; p < 4; ++p) {
                int ci = tid + p*256;
                *(short8*)&Pl[ci>>3][(ci&7)*8] = *(const short8*)(ps + ci*8);
            }
        }
        __syncthreads();

        // ---- AC = qu . K^T : 4 j-frags ----
        f32x4 acc_s[4] = {};
        #pragma unroll
        for (int ks = 0; ks < 2; ++ks)
            #pragma unroll
            for (int jf = 0; jf < 4; ++jf) {
                short8 bf = *(const short8*)&Kl[jf*16 + c][ks*32 + 8*g];
                acc_s[jf] = __builtin_amdgcn_mfma_f32_16x16x32_bf16(qa[ks], bf, acc_s[jf], 0,0,0);
            }
        // ---- BD = qv . P^T : 5 frags (global frag idx 3-w+fi) ----
        f32x4 acc_b[5] = {};
        #pragma unroll
        for (int ks = 0; ks < 2; ++ks)
            #pragma unroll
            for (int fi = 0; fi < 5; ++fi) {
                short8 bf = *(const short8*)&Pl[(3-w+fi)*16 + c][ks*32 + 8*g];
                acc_b[fi] = __builtin_amdgcn_mfma_f32_16x16x32_bf16(qv[ks], bf, acc_b[fi], 0,0,0);
            }
        #pragma unroll
        for (int fi = 0; fi < 5; ++fi)
            #pragma unroll
            for (int r = 0; r < 4; ++r)
                BDs[w][4*g + r][16*fi + c] = acc_b[fi][r];
        __syncthreads();

        // ---- combine (shifted BD) + online softmax ----
        float rmax[4];
        #pragma unroll
        for (int r = 0; r < 4; ++r) rmax[r] = -1e30f;
        #pragma unroll
        for (int jf = 0; jf < 4; ++jf)
            #pragma unroll
            for (int r = 0; r < 4; ++r) {
                int row = 4*g + r;
                float s = acc_s[jf][r] + BDs[w][row][15 - row + 16*jf + c];
                acc_s[jf][r] = s;
                rmax[r] = fmaxf(rmax[r], s);
            }
        #pragma unroll
        for (int r = 0; r < 4; ++r)
            #pragma unroll
            for (int msk = 1; msk < 16; msk <<= 1)
                rmax[r] = fmaxf(rmax[r], __shfl_xor(rmax[r], msk));
        float fs[4], rsum[4];
        #pragma unroll
        for (int r = 0; r < 4; ++r) {
            float mn = fmaxf(m_run[r], rmax[r]);
            fs[r] = __expf(m_run[r] - mn);
            m_run[r] = mn;
            rsum[r] = 0.f;
        }
        #pragma unroll
        for (int jf = 0; jf < 4; ++jf)
            #pragma unroll
            for (int r = 0; r < 4; ++r) {
                float p = __expf(acc_s[jf][r] - m_run[r]);
                rsum[r] += p;
                Pa[w][4*g + r][16*jf + c] = f2bf(p);
            }
        #pragma unroll
        for (int r = 0; r < 4; ++r) {
            #pragma unroll
            for (int msk = 1; msk < 16; msk <<= 1)
                rsum[r] += __shfl_xor(rsum[r], msk);
            l_run[r] = l_run[r]*fs[r] + rsum[r];
        }
        #pragma unroll
        for (int df = 0; df < 4; ++df)
            #pragma unroll
            for (int r = 0; r < 4; ++r)
                acc_o[df][r] *= fs[r];
        __syncthreads();

        // ---- PV: O += P . V ----
        #pragma unroll
        for (int ks = 0; ks < 2; ++ks) {
            short8 pa = *(const short8*)&Pa[w][c][ks*32 + 8*g];
            #pragma unroll
            for (int df = 0; df < 4; ++df) {
                short8 bv = *(const short8*)&Vl[df*16 + c][ks*32 + 8*g];
                acc_o[df] = __builtin_amdgcn_mfma_f32_16x16x32_bf16(pa, bv, acc_o[df], 0,0,0);
            }
        }
    }

    // epilogue: normalize, write token-major (t*BB+b, CH)
    #pragma unroll
    for (int df = 0; df < 4; ++df)
        #pragma unroll
        for (int r = 0; r < 4; ++r) {
            int t = t0 + 16*w + 4*g + r;
            O[((size_t)t*BB + b)*CH + h*HDIM + 16*df + c] = acc_o[df][r] / l_run[r];
        }
}

// ---------------- GLU ----------------
__global__ __launch_bounds__(256)
void glu_kernel(const float* __restrict__ In, float* __restrict__ Out)
{
    size_t idx = (size_t)blockIdx.x*256 + threadIdx.x;
    size_t b = idx >> 18;
    size_t r = idx & (((size_t)1<<18)-1);
    const float* base = In + b*(2*CH*TT);
    float a = base[r];
    float g = base[CH*TT + r];
    Out[idx] = a / (1.f + __expf(-g));
}

// ---------------- depthwise conv + BN + swish, write token-major ----------------
__global__ __launch_bounds__(256)
void dwconv_kernel(const float* __restrict__ In,
                   const float* __restrict__ W,
                   const float* __restrict__ CB,
                   const float* __restrict__ BNG, const float* __restrict__ BNB,
                   const float* __restrict__ BNM, const float* __restrict__ BNV,
                   float* __restrict__ Out)
{
    int c = blockIdx.x, b = blockIdx.y;
    __shared__ float row[TT + KW - 1];
    __shared__ float wv[KW];
    int tid = threadIdx.x;
    const float* base = In + ((size_t)b*CH + c)*TT;
    for (int i = tid; i < TT + KW - 1; i += 256) {
        int tp = i - (KW-1)/2;
        row[i] = (tp >= 0 && tp < TT) ? base[tp] : 0.f;
    }
    if (tid < KW) wv[tid] = W[c*KW + tid];
    float bias = CB[c];
    float scl  = rsqrtf(BNV[c] + EPSV) * BNG[c];
    float sh   = BNB[c];
    float mn   = BNM[c];
    __syncthreads();
    #pragma unroll
    for (int r = 0; r < 4; ++r) {
        int t = tid + 256*r;
        float acc = 0.f;
        #pragma unroll
        for (int k = 0; k < KW; ++k) acc += row[t + k] * wv[k];
        float v = (acc + bias - mn) * scl + sh;
        v = v / (1.f + __expf(-v));
        Out[((size_t)t*BB + b)*CH + c] = v;
    }
}

extern "C" void kernel_launch(void* const* d_in, const int* in_sizes, int n_in,
                              void* d_out, int out_size, void* d_ws, size_t ws_size,
                              hipStream_t stream)
{
    const float* x_in    = (const float*)d_in[0];
    const float* pos_emb = (const float*)d_in[1];
    const float* ffm_w1  = (const float*)d_in[2];
    const float* ffm_b1  = (const float*)d_in[3];
    const float* ffm_w2  = (const float*)d_in[4];
    const float* ffm_b2  = (const float*)d_in[5];
    const float* ff_w1   = (const float*)d_in[6];
    const float* ff_b1   = (const float*)d_in[7];
    const float* ff_w2   = (const float*)d_in[8];
    const float* ff_b2   = (const float*)d_in[9];
    const float* in_w    = (const float*)d_in[10];
    const float* in_b    = (const float*)d_in[11];
    const float* out_w   = (const float*)d_in[12];
    const float* out_b   = (const float*)d_in[13];
    const float* pos_w   = (const float*)d_in[14];
    const float* bias_u  = (const float*)d_in[15];
    const float* bias_v  = (const float*)d_in[16];
    const float* pw1_w   = (const float*)d_in[17];
    const float* pw1_b   = (const float*)d_in[18];
    const float* dw_w    = (const float*)d_in[19];
    const float* dw_b    = (const float*)d_in[20];
    const float* bn_g    = (const float*)d_in[21];
    const float* bn_b    = (const float*)d_in[22];
    const float* bn_m    = (const float*)d_in[23];
    const float* bn_v    = (const float*)d_in[24];
    const float* pw2_w   = (const float*)d_in[25];
    const float* pw2_b   = (const float*)d_in[26];
    const float* ln_g    = (const float*)d_in[27];
    const float* ln_b    = (const float*)d_in[28];

    char* wp = (char*)d_ws;
    auto alloc = [&](size_t bytes) -> void* {
        void* p = wp; wp += (bytes + 255) & ~(size_t)255; return p;
    };
    float* xbuf = (float*)alloc((size_t)TB*CH*4);
    float* ybuf = (float*)alloc((size_t)TB*CH*4);
    float* hbuf = (float*)alloc((size_t)TB*DFFN*4);
    float* pbuf = (float*)alloc((size_t)2*TT*CH*4);
    float* c1   = (float*)alloc((size_t)BB*2*CH*TT*4);
    float* abuf = (float*)alloc((size_t)TB*CH*4);
    float* c2   = (float*)alloc((size_t)BB*CH*TT*4);
    short* qub  = (short*)alloc((size_t)BB*NH*TT*HDIM*2);
    short* qvb  = (short*)alloc((size_t)BB*NH*TT*HDIM*2);
    short* kb   = (short*)alloc((size_t)BB*NH*TT*HDIM*2);
    short* vtb  = (short*)alloc((size_t)BB*NH*TT*HDIM*2);
    short* pbb  = (short*)alloc((size_t)NH*2048*HDIM*2);
    if ((size_t)(wp - (char*)d_ws) > ws_size) return;

    const float* cur = x_in;
    for (int i = 0; i < NL; ++i) {
        const float* lng = ln_g + (size_t)i*5*CH;
        const float* lnb = ln_b + (size_t)i*5*CH;

        // ---- macaron FFN ----
        ln_kernel<<<TB, 256, 0, stream>>>(cur, lng + 0*CH, lnb + 0*CH, ybuf);
        gemm_kernel<1><<<dim3(DFFN/64, TB/64, 1), 256, 0, stream>>>(
            ybuf, CH, 0, ffm_w1 + (size_t)i*DFFN*CH, CH, 0,
            hbuf, DFFN, 1, 0, nullptr, ffm_b1 + (size_t)i*DFFN, nullptr, 1.f,
            TB, DFFN, CH);
        gemm_kernel<0><<<dim3(CH/64, TB/64, 1), 256, 0, stream>>>(
            hbuf, DFFN, 0, ffm_w2 + (size_t)i*CH*DFFN, DFFN, 0,
            xbuf, CH, 1, 0, nullptr, ffm_b2 + (size_t)i*CH, cur, 0.5f,
            TB, CH, DFFN);
        cur = xbuf;

        // ---- rel-pos attention ----
        ln_kernel<<<TB, 256, 0, stream>>>(cur, lng + 1*CH, lnb + 1*CH, ybuf);
        gemm_kernel<0><<<dim3(3*CH/64, TB/64, 1), 256, 0, stream>>>(
            ybuf, CH, 0, in_w + (size_t)i*3*CH*CH, CH, 0,
            hbuf, 3*CH, 1, 0, nullptr, in_b + (size_t)i*3*CH, nullptr, 1.f,
            TB, 3*CH, CH);
        gemm_kernel<0><<<dim3(CH/64, (2*TT-1+63)/64, 1), 256, 0, stream>>>(
            pos_emb, CH, 0, pos_w + (size_t)i*CH*CH, CH, 0,
            pbuf, CH, 1, 0, nullptr, nullptr, nullptr, 1.f,
            2*TT-1, CH, CH);
        prep_kernel<<<(BB*NH*TT*HDIM)/256, 256, 0, stream>>>(
            hbuf, bias_u + (size_t)i*NH*HDIM, bias_v + (size_t)i*NH*HDIM,
            qub, qvb, kb, vtb);
        pt_kernel<<<(NH*2048*HDIM)/256, 256, 0, stream>>>(pbuf, pbb);
        attn_mfma_kernel<<<dim3(TT/64, NH, BB), 256, 0, stream>>>(
            qub, qvb, kb, vtb, pbb, abuf);
        gemm_kernel<0><<<dim3(CH/64, TB/64, 1), 256, 0, stream>>>(
            abuf, CH, 0, out_w + (size_t)i*CH*CH, CH, 0,
            xbuf, CH, 1, 0, nullptr, out_b + (size_t)i*CH, cur, 1.f,
            TB, CH, CH);

        // ---- conv module ----
        ln_kernel<<<TB, 256, 0, stream>>>(cur, lng + 2*CH, lnb + 2*CH, ybuf);
        gemm_kernel<0><<<dim3(TT/64, (2*CH)/64, BB), 256, 0, stream>>>(
            pw1_w + (size_t)i*2*CH*CH, CH, 0, ybuf, BB*CH, CH,
            c1, TT, 1, (long)2*CH*TT, pw1_b + (size_t)i*2*CH, nullptr, nullptr, 1.f,
            2*CH, TT, CH);
        glu_kernel<<<(BB*CH*TT)/256, 256, 0, stream>>>(c1, c2);
        dwconv_kernel<<<dim3(CH, BB), 256, 0, stream>>>(
            c2, dw_w + (size_t)i*CH*KW, dw_b + (size_t)i*CH,
            bn_g + (size_t)i*CH, bn_b + (size_t)i*CH,
            bn_m + (size_t)i*CH, bn_v + (size_t)i*CH, abuf);
        gemm_kernel<0><<<dim3(CH/64, TB/64, 1), 256, 0, stream>>>(
            abuf, CH, 0, pw2_w + (size_t)i*CH*CH, CH, 0,
            xbuf, CH, 1, 0, nullptr, pw2_b + (size_t)i*CH, cur, 1.f,
            TB, CH, CH);

        // ---- second FFN ----
        ln_kernel<<<TB, 256, 0, stream>>>(cur, lng + 3*CH, lnb + 3*CH, ybuf);
        gemm_kernel<1><<<dim3(DFFN/64, TB/64, 1), 256, 0, stream>>>(
            ybuf, CH, 0, ff_w1 + (size_t)i*DFFN*CH, CH, 0,
            hbuf, DFFN, 1, 0, nullptr, ff_b1 + (size_t)i*DFFN, nullptr, 1.f,
            TB, DFFN, CH);
        gemm_kernel<0><<<dim3(CH/64, TB/64, 1), 256, 0, stream>>>(
            hbuf, DFFN, 0, ff_w2 + (size_t)i*CH*DFFN, DFFN, 0,
            xbuf, CH, 1, 0, nullptr, ff_b2 + (size_t)i*CH, cur, 0.5f,
            TB, CH, DFFN);

        // ---- final LN ----
        float* lnout = (i == NL-1) ? (float*)d_out : xbuf;
        ln_kernel<<<TB, 256, 0, stream>>>(xbuf, lng + 4*CH, lnb + 4*CH, lnout);
        cur = xbuf;
    }
}

// Round 3
// 843.215 us; speedup vs baseline: 7.3833x; 1.3666x over previous
//
#include <hip/hip_runtime.h>
#include <math.h>

#define TT 1024
#define BB 4
#define CH 256
#define NH 4
#define HDIM 64
#define DFFN 1024
#define KW 31
#define NL 2
#define TB (TT*BB)
#define EPSV 1e-5f

typedef __attribute__((ext_vector_type(8))) short short8;
typedef __attribute__((ext_vector_type(4))) float f32x4;

__device__ __forceinline__ short f2bf(float f){
    union { float f; unsigned u; } x; x.f = f;
    unsigned r = x.u + 0x7fffu + ((x.u >> 16) & 1u);
    return (short)(r >> 16);
}

// ---------------- batched f32 -> bf16 convert ----------------
struct CvtSeg { const float* src; short* dst; int n; };
struct CvtArgs { CvtSeg seg[20]; };

__global__ __launch_bounds__(256)
void cvt_kernel(CvtArgs args)
{
    CvtSeg s = args.seg[blockIdx.y];
    int i = (blockIdx.x*256 + threadIdx.x)*8;
    if (i >= s.n) return;
    float4 a = *(const float4*)(s.src + i);
    float4 b = *(const float4*)(s.src + i + 4);
    short8 o;
    o[0]=f2bf(a.x); o[1]=f2bf(a.y); o[2]=f2bf(a.z); o[3]=f2bf(a.w);
    o[4]=f2bf(b.x); o[5]=f2bf(b.y); o[6]=f2bf(b.z); o[7]=f2bf(b.w);
    *(short8*)(s.dst + i) = o;
}

// ---------------- LayerNorm: one block per row of 256, templated output ----------------
template<int OUTBF>
__global__ __launch_bounds__(256)
void ln_kernel(const float* __restrict__ X, const float* __restrict__ G,
               const float* __restrict__ Bt, void* __restrict__ Y)
{
    int row = blockIdx.x;
    int c = threadIdx.x;
    float v = X[(size_t)row*CH + c];
    float s = v, s2 = v*v;
    #pragma unroll
    for (int off = 32; off >= 1; off >>= 1) {
        s  += __shfl_xor(s, off);
        s2 += __shfl_xor(s2, off);
    }
    __shared__ float rs[4], rs2[4];
    if ((c & 63) == 0) { rs[c>>6] = s; rs2[c>>6] = s2; }
    __syncthreads();
    s  = rs[0]+rs[1]+rs[2]+rs[3];
    s2 = rs2[0]+rs2[1]+rs2[2]+rs2[3];
    float mean = s * (1.0f/CH);
    float var  = s2 * (1.0f/CH) - mean*mean;
    float inv  = rsqrtf(var + EPSV);
    float o = (v - mean) * inv * G[c] + Bt[c];
    if (OUTBF) ((short*)Y)[(size_t)row*CH + c] = f2bf(o);
    else       ((float*)Y)[(size_t)row*CH + c] = o;
}

// ---------------- bf16 MFMA GEMM ----------------
// C[m,n] = R + scale*act(sum_k A[m,k]*B[n,k] + biasM[m] + biasN[n])
// A,B bf16 row-contiguous in k. C fp32 (with optional fp32 residual) or bf16.
template<int ACT, int OUTBF>
__global__ __launch_bounds__(256)
void gemm_bf(const short* __restrict__ A, int lda, long sA,
             const short* __restrict__ Bm, int ldb, long sB,
             void* __restrict__ Cv, long ldcm, long ldcn, long sC,
             const float* __restrict__ biasM, const float* __restrict__ biasN,
             const float* __restrict__ Rm, float scale,
             int M, int N, int Kd)
{
    __shared__ short As[128][72];
    __shared__ short Bs[128][72];
    const int bz = blockIdx.z;
    A  += (long)bz * sA;
    Bm += (long)bz * sB;
    const int m0 = blockIdx.y * 128;
    const int n0 = blockIdx.x * 128;
    const int tid = threadIdx.x;
    const int w = tid >> 6, lane = tid & 63;
    const int g = lane >> 4, c = lane & 15;
    const int wr = w >> 1, wc = w & 1;
    const int srow = tid >> 3, scol = (tid & 7) * 8;

    f32x4 acc[4][4] = {};
    for (int kt = 0; kt < Kd; kt += 64) {
        __syncthreads();
        #pragma unroll
        for (int p = 0; p < 4; ++p) {
            int r = srow + p*32;
            int gm = m0 + r; if (gm >= M) gm = M - 1;
            *(short8*)&As[r][scol] = *(const short8*)(A + (long)gm*lda + kt + scol);
            int gn = n0 + r; if (gn >= N) gn = N - 1;
            *(short8*)&Bs[r][scol] = *(const short8*)(Bm + (long)gn*ldb + kt + scol);
        }
        __syncthreads();
        #pragma unroll
        for (int ks = 0; ks < 2; ++ks) {
            short8 af[4], bf[4];
            #pragma unroll
            for (int i = 0; i < 4; ++i) af[i] = *(const short8*)&As[wr*64 + i*16 + c][ks*32 + 8*g];
            #pragma unroll
            for (int j = 0; j < 4; ++j) bf[j] = *(const short8*)&Bs[wc*64 + j*16 + c][ks*32 + 8*g];
            #pragma unroll
            for (int i = 0; i < 4; ++i)
                #pragma unroll
                for (int j = 0; j < 4; ++j)
                    acc[i][j] = __builtin_amdgcn_mfma_f32_16x16x32_bf16(af[i], bf[j], acc[i][j], 0,0,0);
        }
    }

    #pragma unroll
    for (int i = 0; i < 4; ++i) {
        #pragma unroll
        for (int r = 0; r < 4; ++r) {
            int m = m0 + wr*64 + i*16 + 4*g + r;
            if (m >= M) continue;
            float bm = biasM ? biasM[m] : 0.f;
            #pragma unroll
            for (int j = 0; j < 4; ++j) {
                int n = n0 + wc*64 + j*16 + c;
                if (n >= N) continue;
                float v = acc[i][j][r] + bm + (biasN ? biasN[n] : 0.f);
                if (ACT == 1) v = v / (1.f + __expf(-v));
                v *= scale;
                long ci = (long)m*ldcm + (long)n*ldcn;
                if (OUTBF) {
                    ((short*)Cv)[(long)bz*sC + ci] = f2bf(v);
                } else {
                    float* Cf = (float*)Cv + (long)bz*sC;
                    if (Rm) v += (Rm + (long)bz*sC)[ci];
                    Cf[ci] = v;
                }
            }
        }
    }
}

// ---------------- qkv(fp32) -> bf16 qu, qv, k (bh,t,d) and v transposed (bh,d,t) ----------------
__global__ __launch_bounds__(256)
void prep_kernel(const float* __restrict__ QKV, const float* __restrict__ BU,
                 const float* __restrict__ BV,
                 short* __restrict__ qub, short* __restrict__ qvb,
                 short* __restrict__ kb, short* __restrict__ vtb)
{
    int idx = blockIdx.x*256 + threadIdx.x;
    int d = idx & 63;
    int t = (idx >> 6)  & (TT-1);
    int h = (idx >> 16) & (NH-1);
    int b = idx >> 18;
    size_t src = ((size_t)(t*BB + b))*(3*CH) + h*HDIM + d;
    float q = QKV[src] * 0.125f;
    qub[idx] = f2bf(q + BU[h*HDIM + d]);
    qvb[idx] = f2bf(q + BV[h*HDIM + d]);
    kb[idx]  = f2bf(QKV[src + CH]);
    int bh = b*NH + h;
    vtb[((size_t)bh*HDIM + d)*TT + t] = f2bf(QKV[src + 2*CH]);
}

// ---------------- projected pos (bf16, (2T-1,CH)) -> (h, 2048, 64), row 2047 zeroed ----------------
__global__ __launch_bounds__(256)
void pt_kernel(const short* __restrict__ P, short* __restrict__ pbf)
{
    int idx = blockIdx.x*256 + threadIdx.x;
    int d = idx & 63;
    int n = (idx >> 6) & 2047;
    short v = (n < 2*TT-1) ? P[(size_t)n*CH + (idx>>17)*HDIM + d] : (short)0;
    pbf[idx] = v;
}

// ---------------- MFMA flash attention with fused rel_shift ----------------
__global__ __launch_bounds__(256)
void attn_mfma_kernel(const short* __restrict__ qub, const short* __restrict__ qvb,
                      const short* __restrict__ kb, const short* __restrict__ vtb,
                      const short* __restrict__ pbf, short* __restrict__ O)
{
    const int t0 = blockIdx.x * 64;
    const int h  = blockIdx.y, b = blockIdx.z;
    const int bh = b*NH + h;
    const int tid = threadIdx.x;
    const int w = tid >> 6, lane = tid & 63;
    const int g = lane >> 4, c = lane & 15;

    __shared__ short Kl[64][88];
    __shared__ short Vl[64][88];
    __shared__ short Pl[128][88];
    __shared__ float BDs[4][16][84];
    __shared__ short Pa[4][16][88];

    short8 qa[2], qv[2];
    {
        const short* qr = qub + ((size_t)bh*TT + t0 + 16*w + c)*HDIM;
        const short* vr = qvb + ((size_t)bh*TT + t0 + 16*w + c)*HDIM;
        qa[0] = *(const short8*)(qr + 8*g);
        qa[1] = *(const short8*)(qr + 32 + 8*g);
        qv[0] = *(const short8*)(vr + 8*g);
        qv[1] = *(const short8*)(vr + 32 + 8*g);
    }

    f32x4 acc_o[4] = {};
    float m_run[4], l_run[4];
    #pragma unroll
    for (int r = 0; r < 4; ++r){ m_run[r] = -1e30f; l_run[r] = 0.f; }

    for (int jt = 0; jt < 16; ++jt) {
        const int j0 = jt*64;
        const int nb = 960 - t0 + j0;
        __syncthreads();
        {
            const short* src = kb + ((size_t)bh*TT + j0)*HDIM;
            #pragma unroll
            for (int p = 0; p < 2; ++p) {
                int ci = tid + p*256;
                *(short8*)&Kl[ci>>3][(ci&7)*8] = *(const short8*)(src + ci*8);
            }
            #pragma unroll
            for (int p = 0; p < 2; ++p) {
                int ci = tid + p*256;
                *(short8*)&Vl[ci>>3][(ci&7)*8] =
                    *(const short8*)(vtb + ((size_t)bh*HDIM + (ci>>3))*TT + j0 + (ci&7)*8);
            }
            const short* ps = pbf + ((size_t)h*2048 + nb)*HDIM;
            #pragma unroll
            for (int p = 0; p < 4; ++p) {
                int ci = tid + p*256;
                *(short8*)&Pl[ci>>3][(ci&7)*8] = *(const short8*)(ps + ci*8);
            }
        }
        __syncthreads();

        f32x4 acc_s[4] = {};
        #pragma unroll
        for (int ks = 0; ks < 2; ++ks)
            #pragma unroll
            for (int jf = 0; jf < 4; ++jf) {
                short8 bf = *(const short8*)&Kl[jf*16 + c][ks*32 + 8*g];
                acc_s[jf] = __builtin_amdgcn_mfma_f32_16x16x32_bf16(qa[ks], bf, acc_s[jf], 0,0,0);
            }
        f32x4 acc_b[5] = {};
        #pragma unroll
        for (int ks = 0; ks < 2; ++ks)
            #pragma unroll
            for (int fi = 0; fi < 5; ++fi) {
                short8 bf = *(const short8*)&Pl[(3-w+fi)*16 + c][ks*32 + 8*g];
                acc_b[fi] = __builtin_amdgcn_mfma_f32_16x16x32_bf16(qv[ks], bf, acc_b[fi], 0,0,0);
            }
        #pragma unroll
        for (int fi = 0; fi < 5; ++fi)
            #pragma unroll
            for (int r = 0; r < 4; ++r)
                BDs[w][4*g + r][16*fi + c] = acc_b[fi][r];
        __syncthreads();

        float rmax[4];
        #pragma unroll
        for (int r = 0; r < 4; ++r) rmax[r] = -1e30f;
        #pragma unroll
        for (int jf = 0; jf < 4; ++jf)
            #pragma unroll
            for (int r = 0; r < 4; ++r) {
                int row = 4*g + r;
                float s = acc_s[jf][r] + BDs[w][row][15 - row + 16*jf + c];
                acc_s[jf][r] = s;
                rmax[r] = fmaxf(rmax[r], s);
            }
        #pragma unroll
        for (int r = 0; r < 4; ++r)
            #pragma unroll
            for (int msk = 1; msk < 16; msk <<= 1)
                rmax[r] = fmaxf(rmax[r], __shfl_xor(rmax[r], msk));
        float fs[4], rsum[4];
        #pragma unroll
        for (int r = 0; r < 4; ++r) {
            float mn = fmaxf(m_run[r], rmax[r]);
            fs[r] = __expf(m_run[r] - mn);
            m_run[r] = mn;
            rsum[r] = 0.f;
        }
        #pragma unroll
        for (int jf = 0; jf < 4; ++jf)
            #pragma unroll
            for (int r = 0; r < 4; ++r) {
                float p = __expf(acc_s[jf][r] - m_run[r]);
                rsum[r] += p;
                Pa[w][4*g + r][16*jf + c] = f2bf(p);
            }
        #pragma unroll
        for (int r = 0; r < 4; ++r) {
            #pragma unroll
            for (int msk = 1; msk < 16; msk <<= 1)
                rsum[r] += __shfl_xor(rsum[r], msk);
            l_run[r] = l_run[r]*fs[r] + rsum[r];
        }
        #pragma unroll
        for (int df = 0; df < 4; ++df)
            #pragma unroll
            for (int r = 0; r < 4; ++r)
                acc_o[df][r] *= fs[r];
        __syncthreads();

        #pragma unroll
        for (int ks = 0; ks < 2; ++ks) {
            short8 pa = *(const short8*)&Pa[w][c][ks*32 + 8*g];
            #pragma unroll
            for (int df = 0; df < 4; ++df) {
                short8 bv = *(const short8*)&Vl[df*16 + c][ks*32 + 8*g];
                acc_o[df] = __builtin_amdgcn_mfma_f32_16x16x32_bf16(pa, bv, acc_o[df], 0,0,0);
            }
        }
    }

    #pragma unroll
    for (int df = 0; df < 4; ++df)
        #pragma unroll
        for (int r = 0; r < 4; ++r) {
            int t = t0 + 16*w + 4*g + r;
            O[((size_t)t*BB + b)*CH + h*HDIM + 16*df + c] = f2bf(acc_o[df][r] / l_run[r]);
        }
}

// ---------------- GLU ----------------
__global__ __launch_bounds__(256)
void glu_kernel(const float* __restrict__ In, float* __restrict__ Out)
{
    size_t idx = (size_t)blockIdx.x*256 + threadIdx.x;
    size_t b = idx >> 18;
    size_t r = idx & (((size_t)1<<18)-1);
    const float* base = In + b*(2*CH*TT);
    float a = base[r];
    float g = base[CH*TT + r];
    Out[idx] = a / (1.f + __expf(-g));
}

// ---------------- depthwise conv + BN + swish, write token-major bf16 ----------------
__global__ __launch_bounds__(256)
void dwconv_kernel(const float* __restrict__ In,
                   const float* __restrict__ W,
                   const float* __restrict__ CB,
                   const float* __restrict__ BNG, const float* __restrict__ BNB,
                   const float* __restrict__ BNM, const float* __restrict__ BNV,
                   short* __restrict__ Out)
{
    int c = blockIdx.x, b = blockIdx.y;
    __shared__ float row[TT + KW - 1];
    __shared__ float wv[KW];
    int tid = threadIdx.x;
    const float* base = In + ((size_t)b*CH + c)*TT;
    for (int i = tid; i < TT + KW - 1; i += 256) {
        int tp = i - (KW-1)/2;
        row[i] = (tp >= 0 && tp < TT) ? base[tp] : 0.f;
    }
    if (tid < KW) wv[tid] = W[c*KW + tid];
    float bias = CB[c];
    float scl  = rsqrtf(BNV[c] + EPSV) * BNG[c];
    float sh   = BNB[c];
    float mn   = BNM[c];
    __syncthreads();
    #pragma unroll
    for (int r = 0; r < 4; ++r) {
        int t = tid + 256*r;
        float acc = 0.f;
        #pragma unroll
        for (int k = 0; k < KW; ++k) acc += row[t + k] * wv[k];
        float v = (acc + bias - mn) * scl + sh;
        v = v / (1.f + __expf(-v));
        Out[((size_t)t*BB + b)*CH + c] = f2bf(v);
    }
}

extern "C" void kernel_launch(void* const* d_in, const int* in_sizes, int n_in,
                              void* d_out, int out_size, void* d_ws, size_t ws_size,
                              hipStream_t stream)
{
    const float* x_in    = (const float*)d_in[0];
    const float* pos_emb = (const float*)d_in[1];
    const float* ffm_w1  = (const float*)d_in[2];
    const float* ffm_b1  = (const float*)d_in[3];
    const float* ffm_w2  = (const float*)d_in[4];
    const float* ffm_b2  = (const float*)d_in[5];
    const float* ff_w1   = (const float*)d_in[6];
    const float* ff_b1   = (const float*)d_in[7];
    const float* ff_w2   = (const float*)d_in[8];
    const float* ff_b2   = (const float*)d_in[9];
    const float* in_w    = (const float*)d_in[10];
    const float* in_b    = (const float*)d_in[11];
    const float* out_w   = (const float*)d_in[12];
    const float* out_b   = (const float*)d_in[13];
    const float* pos_w   = (const float*)d_in[14];
    const float* bias_u  = (const float*)d_in[15];
    const float* bias_v  = (const float*)d_in[16];
    const float* pw1_w   = (const float*)d_in[17];
    const float* pw1_b   = (const float*)d_in[18];
    const float* dw_w    = (const float*)d_in[19];
    const float* dw_b    = (const float*)d_in[20];
    const float* bn_g    = (const float*)d_in[21];
    const float* bn_b    = (const float*)d_in[22];
    const float* bn_m    = (const float*)d_in[23];
    const float* bn_v    = (const float*)d_in[24];
    const float* pw2_w   = (const float*)d_in[25];
    const float* pw2_b   = (const float*)d_in[26];
    const float* ln_g    = (const float*)d_in[27];
    const float* ln_b    = (const float*)d_in[28];

    char* wp = (char*)d_ws;
    auto alloc = [&](size_t bytes) -> void* {
        void* p = wp; wp += (bytes + 255) & ~(size_t)255; return p;
    };
    float* xbuf   = (float*)alloc((size_t)TB*CH*4);
    short* ybf    = (short*)alloc((size_t)TB*CH*2);
    float* qkvbuf = (float*)alloc((size_t)TB*3*CH*4);
    short* hff    = (short*)alloc((size_t)TB*DFFN*2);
    short* pbf    = (short*)alloc((size_t)(2*TT)*CH*2);
    float* c1     = (float*)alloc((size_t)BB*2*CH*TT*4);
    float* c2     = (float*)alloc((size_t)BB*CH*TT*4);
    short* abf    = (short*)alloc((size_t)TB*CH*2);
    short* qub    = (short*)alloc((size_t)BB*NH*TT*HDIM*2);
    short* qvb    = (short*)alloc((size_t)BB*NH*TT*HDIM*2);
    short* kb     = (short*)alloc((size_t)BB*NH*TT*HDIM*2);
    short* vtb    = (short*)alloc((size_t)BB*NH*TT*HDIM*2);
    short* pbb    = (short*)alloc((size_t)NH*2048*HDIM*2);
    // bf16 weights
    short* wbf[NL][9];
    const float* wsrc[NL][9];
    int    wn[9] = { DFFN*CH, CH*DFFN, DFFN*CH, CH*DFFN, 3*CH*CH, CH*CH, CH*CH, 2*CH*CH, CH*CH };
    for (int i = 0; i < NL; ++i) {
        const float* srcs[9] = {
            ffm_w1 + (size_t)i*DFFN*CH, ffm_w2 + (size_t)i*CH*DFFN,
            ff_w1  + (size_t)i*DFFN*CH, ff_w2  + (size_t)i*CH*DFFN,
            in_w   + (size_t)i*3*CH*CH, out_w  + (size_t)i*CH*CH,
            pos_w  + (size_t)i*CH*CH,   pw1_w  + (size_t)i*2*CH*CH,
            pw2_w  + (size_t)i*CH*CH };
        for (int j = 0; j < 9; ++j) {
            wsrc[i][j] = srcs[j];
            wbf[i][j]  = (short*)alloc((size_t)wn[j]*2);
        }
    }
    short* posbf = (short*)alloc((size_t)(2*TT-1)*CH*2);
    if ((size_t)(wp - (char*)d_ws) > ws_size) return;

    // one-shot conversions (weights + pos_emb)
    CvtArgs ca;
    int nseg = 0, maxn = 0;
    for (int i = 0; i < NL; ++i)
        for (int j = 0; j < 9; ++j) {
            ca.seg[nseg++] = { wsrc[i][j], wbf[i][j], wn[j] };
            if (wn[j] > maxn) maxn = wn[j];
        }
    ca.seg[nseg++] = { pos_emb, posbf, (2*TT-1)*CH };
    if ((2*TT-1)*CH > maxn) maxn = (2*TT-1)*CH;
    cvt_kernel<<<dim3((maxn/8 + 255)/256, nseg), 256, 0, stream>>>(ca);

    const float* cur = x_in;
    for (int i = 0; i < NL; ++i) {
        const float* lng = ln_g + (size_t)i*5*CH;
        const float* lnb = ln_b + (size_t)i*5*CH;

        // ---- macaron FFN ----
        ln_kernel<1><<<TB, 256, 0, stream>>>(cur, lng + 0*CH, lnb + 0*CH, ybf);
        gemm_bf<1,1><<<dim3(DFFN/128, TB/128), 256, 0, stream>>>(
            ybf, CH, 0, wbf[i][0], CH, 0, hff, DFFN, 1, 0,
            nullptr, ffm_b1 + (size_t)i*DFFN, nullptr, 1.f, TB, DFFN, CH);
        gemm_bf<0,0><<<dim3(CH/128, TB/128), 256, 0, stream>>>(
            hff, DFFN, 0, wbf[i][1], DFFN, 0, xbuf, CH, 1, 0,
            nullptr, ffm_b2 + (size_t)i*CH, cur, 0.5f, TB, CH, DFFN);
        cur = xbuf;

        // ---- rel-pos attention ----
        ln_kernel<1><<<TB, 256, 0, stream>>>(cur, lng + 1*CH, lnb + 1*CH, ybf);
        gemm_bf<0,0><<<dim3(3*CH/128, TB/128), 256, 0, stream>>>(
            ybf, CH, 0, wbf[i][4], CH, 0, qkvbuf, 3*CH, 1, 0,
            nullptr, in_b + (size_t)i*3*CH, nullptr, 1.f, TB, 3*CH, CH);
        gemm_bf<0,1><<<dim3(CH/128, (2*TT-1+127)/128), 256, 0, stream>>>(
            posbf, CH, 0, wbf[i][6], CH, 0, pbf, CH, 1, 0,
            nullptr, nullptr, nullptr, 1.f, 2*TT-1, CH, CH);
        prep_kernel<<<(BB*NH*TT*HDIM)/256, 256, 0, stream>>>(
            qkvbuf, bias_u + (size_t)i*NH*HDIM, bias_v + (size_t)i*NH*HDIM,
            qub, qvb, kb, vtb);
        pt_kernel<<<(NH*2048*HDIM)/256, 256, 0, stream>>>(pbf, pbb);
        attn_mfma_kernel<<<dim3(TT/64, NH, BB), 256, 0, stream>>>(
            qub, qvb, kb, vtb, pbb, abf);
        gemm_bf<0,0><<<dim3(CH/128, TB/128), 256, 0, stream>>>(
            abf, CH, 0, wbf[i][5], CH, 0, xbuf, CH, 1, 0,
            nullptr, out_b + (size_t)i*CH, cur, 1.f, TB, CH, CH);

        // ---- conv module ----
        ln_kernel<1><<<TB, 256, 0, stream>>>(cur, lng + 2*CH, lnb + 2*CH, ybf);
        gemm_bf<0,0><<<dim3(TT/128, (2*CH)/128, BB), 256, 0, stream>>>(
            wbf[i][7], CH, 0, ybf, BB*CH, CH, c1, TT, 1, (long)2*CH*TT,
            pw1_b + (size_t)i*2*CH, nullptr, nullptr, 1.f, 2*CH, TT, CH);
        glu_kernel<<<(BB*CH*TT)/256, 256, 0, stream>>>(c1, c2);
        dwconv_kernel<<<dim3(CH, BB), 256, 0, stream>>>(
            c2, dw_w + (size_t)i*CH*KW, dw_b + (size_t)i*CH,
            bn_g + (size_t)i*CH, bn_b + (size_t)i*CH,
            bn_m + (size_t)i*CH, bn_v + (size_t)i*CH, abf);
        gemm_bf<0,0><<<dim3(CH/128, TB/128), 256, 0, stream>>>(
            abf, CH, 0, wbf[i][8], CH, 0, xbuf, CH, 1, 0,
            nullptr, pw2_b + (size_t)i*CH, cur, 1.f, TB, CH, CH);

        // ---- second FFN ----
        ln_kernel<1><<<TB, 256, 0, stream>>>(cur, lng + 3*CH, lnb + 3*CH, ybf);
        gemm_bf<1,1><<<dim3(DFFN/128, TB/128), 256, 0, stream>>>(
            ybf, CH, 0, wbf[i][2], CH, 0, hff, DFFN, 1, 0,
            nullptr, ff_b1 + (size_t)i*DFFN, nullptr, 1.f, TB, DFFN, CH);
        gemm_bf<0,0><<<dim3(CH/128, TB/128), 256, 0, stream>>>(
            hff, DFFN, 0, wbf[i][3], DFFN, 0, xbuf, CH, 1, 0,
            nullptr, ff_b2 + (size_t)i*CH, cur, 0.5f, TB, CH, DFFN);

        // ---- final LN ----
        if (i == NL-1)
            ln_kernel<0><<<TB, 256, 0, stream>>>(xbuf, lng + 4*CH, lnb + 4*CH, (float*)d_out);
        else
            ln_kernel<0><<<TB, 256, 0, stream>>>(xbuf, lng + 4*CH, lnb + 4*CH, xbuf);
        cur = xbuf;
    }
}

// Round 5
// 555.142 us; speedup vs baseline: 11.2146x; 1.5189x over previous
//
#include <hip/hip_runtime.h>
#include <math.h>

#define TT 1024
#define BB 4
#define CH 256
#define NH 4
#define HDIM 64
#define DFFN 1024
#define KW 31
#define NL 2
#define TB (TT*BB)
#define EPSV 1e-5f

typedef __attribute__((ext_vector_type(8))) short short8;
typedef __attribute__((ext_vector_type(4))) short short4v;
typedef __attribute__((ext_vector_type(4))) float f32x4;

__device__ __forceinline__ short f2bf(float f){
    union { float f; unsigned u; } x; x.f = f;
    unsigned r = x.u + 0x7fffu + ((x.u >> 16) & 1u);
    return (short)(r >> 16);
}

// ---------------- batched f32 -> bf16 convert (mode 1 = pw1 row-interleave) ----------------
struct CvtSeg { const float* src; short* dst; int n; int mode; };
struct CvtArgs { CvtSeg seg[20]; };

__global__ __launch_bounds__(256)
void cvt_kernel(CvtArgs args)
{
    CvtSeg s = args.seg[blockIdx.y];
    int i = (blockIdx.x*256 + threadIdx.x)*8;
    if (i >= s.n) return;
    float4 a = *(const float4*)(s.src + i);
    float4 b = *(const float4*)(s.src + i + 4);
    short8 o;
    o[0]=f2bf(a.x); o[1]=f2bf(a.y); o[2]=f2bf(a.z); o[3]=f2bf(a.w);
    o[4]=f2bf(b.x); o[5]=f2bf(b.y); o[6]=f2bf(b.z); o[7]=f2bf(b.w);
    int di = i;
    if (s.mode == 1) {            // pw1 (512x256): src row c -> dst row (c<256 ? 2c : 2(c-256)+1)
        int c = i >> 8, k = i & 255;
        int dr = (c < 256) ? 2*c : 2*(c-256)+1;
        di = dr*256 + k;
    }
    *(short8*)(s.dst + di) = o;
}

// ---------------- LayerNorm: 4 rows/block, float4 per lane, wave reduce ----------------
template<int OUTBF>
__global__ __launch_bounds__(256)
void ln_kernel(const float* __restrict__ X, const float* __restrict__ G,
               const float* __restrict__ Bt, void* __restrict__ Y)
{
    int row  = blockIdx.x*4 + (threadIdx.x >> 6);
    int lane = threadIdx.x & 63;
    float4 v = ((const float4*)X)[(size_t)row*64 + lane];
    float s  = v.x + v.y + v.z + v.w;
    float s2 = v.x*v.x + v.y*v.y + v.z*v.z + v.w*v.w;
    #pragma unroll
    for (int off = 32; off >= 1; off >>= 1) {
        s  += __shfl_xor(s, off);
        s2 += __shfl_xor(s2, off);
    }
    float mean = s * (1.0f/CH);
    float var  = s2 * (1.0f/CH) - mean*mean;
    float inv  = rsqrtf(var + EPSV);
    float4 g4 = ((const float4*)G)[lane];
    float4 b4 = ((const float4*)Bt)[lane];
    float o0 = (v.x-mean)*inv*g4.x + b4.x;
    float o1 = (v.y-mean)*inv*g4.y + b4.y;
    float o2 = (v.z-mean)*inv*g4.z + b4.z;
    float o3 = (v.w-mean)*inv*g4.w + b4.w;
    if (OUTBF) {
        short4v o; o[0]=f2bf(o0); o[1]=f2bf(o1); o[2]=f2bf(o2); o[3]=f2bf(o3);
        *(short4v*)((short*)Y + (size_t)row*CH + lane*4) = o;
    } else {
        float4 o = {o0,o1,o2,o3};
        ((float4*)Y)[(size_t)row*64 + lane] = o;
    }
}

// ---------------- bf16 MFMA GEMM, 64x64 tile, fused epilogues ----------------
// ACT: 0 none, 1 swish, 2 GLU(pw1, interleaved weights), 3 QKV-prep, 4 POS-scatter
template<int ACT, int OUTBF>
__global__ __launch_bounds__(256)
void gemm_bf(const short* __restrict__ A, int lda, long sA,
             const short* __restrict__ Bm, int ldb, long sB,
             void* __restrict__ Cv, long ldcm, long ldcn, long sC,
             const float* __restrict__ biasM, const float* __restrict__ biasN,
             const float* __restrict__ Rm, float scale,
             int M, int N, int Kd,
             short* __restrict__ x1, short* __restrict__ x2,
             short* __restrict__ x3, short* __restrict__ x4,
             const float* __restrict__ f1, const float* __restrict__ f2)
{
    __shared__ short As[64][72];
    __shared__ short Bs[64][72];
    const int bz = blockIdx.z;
    A  += (long)bz * sA;
    Bm += (long)bz * sB;
    const int m0 = blockIdx.y * 64;
    const int n0 = blockIdx.x * 64;
    const int tid = threadIdx.x;
    const int w = tid >> 6, lane = tid & 63;
    const int g = lane >> 4, c = lane & 15;
    const int wr = w >> 1, wc = w & 1;
    const int srow = tid >> 3, scol = (tid & 7) * 8;

    f32x4 acc[2][2] = {};
    for (int kt = 0; kt < Kd; kt += 64) {
        __syncthreads();
        #pragma unroll
        for (int p = 0; p < 2; ++p) {
            int r = srow + p*32;
            int gm = m0 + r; if (gm >= M) gm = M - 1;
            *(short8*)&As[r][scol] = *(const short8*)(A + (long)gm*lda + kt + scol);
            int gn = n0 + r; if (gn >= N) gn = N - 1;
            *(short8*)&Bs[r][scol] = *(const short8*)(Bm + (long)gn*ldb + kt + scol);
        }
        __syncthreads();
        #pragma unroll
        for (int ks = 0; ks < 2; ++ks) {
            short8 af[2], bf[2];
            #pragma unroll
            for (int i = 0; i < 2; ++i) af[i] = *(const short8*)&As[wr*32 + i*16 + c][ks*32 + 8*g];
            #pragma unroll
            for (int j = 0; j < 2; ++j) bf[j] = *(const short8*)&Bs[wc*32 + j*16 + c][ks*32 + 8*g];
            #pragma unroll
            for (int i = 0; i < 2; ++i)
                #pragma unroll
                for (int j = 0; j < 2; ++j)
                    acc[i][j] = __builtin_amdgcn_mfma_f32_16x16x32_bf16(af[i], bf[j], acc[i][j], 0,0,0);
        }
    }

    if (ACT == 3) {
        // QKV prep: A=ln(x) tokens (m = t*BB+b), B=in_w rows (n in 0..767)
        // region uniform per block: n0>>8 -> 0:q 1:k 2:v
        const int region = n0 >> 8;
        #pragma unroll
        for (int i = 0; i < 2; ++i)
            #pragma unroll
            for (int r = 0; r < 4; ++r) {
                int m = m0 + wr*32 + i*16 + 4*g + r;
                int t = m >> 2, b = m & 3;
                #pragma unroll
                for (int j = 0; j < 2; ++j) {
                    int n = n0 + wc*32 + j*16 + c;
                    float v = acc[i][j][r] + biasN[n];
                    int h = (n >> 6) & 3, d = n & 63;
                    int bh = b*NH + h;
                    if (region == 0) {
                        float q = v * 0.125f;
                        size_t di = ((size_t)bh*TT + t)*HDIM + d;
                        x1[di] = f2bf(q + f1[h*HDIM + d]);
                        x2[di] = f2bf(q + f2[h*HDIM + d]);
                    } else if (region == 1) {
                        x3[((size_t)bh*TT + t)*HDIM + d] = f2bf(v);
                    } else {
                        x4[((size_t)bh*HDIM + d)*TT + t] = f2bf(v);
                    }
                }
            }
        return;
    }
    if (ACT == 4) {
        // POS scatter: m = pos row (0..2046), n -> (h,d); dst (h,2048,64)
        #pragma unroll
        for (int i = 0; i < 2; ++i)
            #pragma unroll
            for (int r = 0; r < 4; ++r) {
                int m = m0 + wr*32 + i*16 + 4*g + r;
                if (m >= M) continue;
                #pragma unroll
                for (int j = 0; j < 2; ++j) {
                    int n = n0 + wc*32 + j*16 + c;
                    int h = n >> 6, d = n & 63;
                    x1[((size_t)h*2048 + m)*HDIM + d] = f2bf(acc[i][j][r]);
                }
            }
        return;
    }
    if (ACT == 2) {
        // GLU: interleaved rows (even=a, odd=g); out channel m>>1; C shape (B,CH,TT) fp32
        float* Cf = (float*)Cv + (long)bz*sC;
        #pragma unroll
        for (int i = 0; i < 2; ++i)
            #pragma unroll
            for (int rp = 0; rp < 2; ++rp) {
                int ma = m0 + wr*32 + i*16 + 4*g + 2*rp;
                float va = acc[i][0][2*rp]   + biasM[ma>>1];          // a-half bias idx = c
                float vg = acc[i][0][2*rp+1] + biasM[(ma>>1)+CH];     // g-half bias idx = c+CH
                float vb = acc[i][1][2*rp]   + biasM[ma>>1];
                float hg = acc[i][1][2*rp+1] + biasM[(ma>>1)+CH];
                #pragma unroll
                for (int j = 0; j < 2; ++j) {
                    int n = n0 + wc*32 + j*16 + c;
                    float a = j ? vb : va;
                    float gg = j ? hg : vg;
                    Cf[(long)(ma>>1)*ldcm + n] = a / (1.f + __expf(-gg));
                }
            }
        return;
    }

    #pragma unroll
    for (int i = 0; i < 2; ++i) {
        #pragma unroll
        for (int r = 0; r < 4; ++r) {
            int m = m0 + wr*32 + i*16 + 4*g + r;
            if (m >= M) continue;
            float bm = biasM ? biasM[m] : 0.f;
            #pragma unroll
            for (int j = 0; j < 2; ++j) {
                int n = n0 + wc*32 + j*16 + c;
                if (n >= N) continue;
                float v = acc[i][j][r] + bm + (biasN ? biasN[n] : 0.f);
                if (ACT == 1) v = v / (1.f + __expf(-v));
                v *= scale;
                long ci = (long)m*ldcm + (long)n*ldcn;
                if (OUTBF) {
                    ((short*)Cv)[(long)bz*sC + ci] = f2bf(v);
                } else {
                    float* Cf = (float*)Cv + (long)bz*sC;
                    if (Rm) v += (Rm + (long)bz*sC)[ci];
                    Cf[ci] = v;
                }
            }
        }
    }
}

// ---------------- MFMA flash attention with fused rel_shift ----------------
__global__ __launch_bounds__(256)
void attn_mfma_kernel(const short* __restrict__ qub, const short* __restrict__ qvb,
                      const short* __restrict__ kb, const short* __restrict__ vtb,
                      const short* __restrict__ pbf, short* __restrict__ O)
{
    const int t0 = blockIdx.x * 64;
    const int h  = blockIdx.y, b = blockIdx.z;
    const int bh = b*NH + h;
    const int tid = threadIdx.x;
    const int w = tid >> 6, lane = tid & 63;
    const int g = lane >> 4, c = lane & 15;

    __shared__ short Kl[64][88];
    __shared__ short Vl[64][88];
    __shared__ short Pl[128][88];
    __shared__ float BDs[4][16][84];
    __shared__ short Pa[4][16][88];

    short8 qa[2], qv[2];
    {
        const short* qr = qub + ((size_t)bh*TT + t0 + 16*w + c)*HDIM;
        const short* vr = qvb + ((size_t)bh*TT + t0 + 16*w + c)*HDIM;
        qa[0] = *(const short8*)(qr + 8*g);
        qa[1] = *(const short8*)(qr + 32 + 8*g);
        qv[0] = *(const short8*)(vr + 8*g);
        qv[1] = *(const short8*)(vr + 32 + 8*g);
    }

    f32x4 acc_o[4] = {};
    float m_run[4], l_run[4];
    #pragma unroll
    for (int r = 0; r < 4; ++r){ m_run[r] = -1e30f; l_run[r] = 0.f; }

    for (int jt = 0; jt < 16; ++jt) {
        const int j0 = jt*64;
        const int nb = 960 - t0 + j0;
        __syncthreads();
        {
            const short* src = kb + ((size_t)bh*TT + j0)*HDIM;
            #pragma unroll
            for (int p = 0; p < 2; ++p) {
                int ci = tid + p*256;
                *(short8*)&Kl[ci>>3][(ci&7)*8] = *(const short8*)(src + ci*8);
            }
            #pragma unroll
            for (int p = 0; p < 2; ++p) {
                int ci = tid + p*256;
                *(short8*)&Vl[ci>>3][(ci&7)*8] =
                    *(const short8*)(vtb + ((size_t)bh*HDIM + (ci>>3))*TT + j0 + (ci&7)*8);
            }
            const short* ps = pbf + ((size_t)h*2048 + nb)*HDIM;
            #pragma unroll
            for (int p = 0; p < 4; ++p) {
                int ci = tid + p*256;
                *(short8*)&Pl[ci>>3][(ci&7)*8] = *(const short8*)(ps + ci*8);
            }
        }
        __syncthreads();

        f32x4 acc_s[4] = {};
        #pragma unroll
        for (int ks = 0; ks < 2; ++ks)
            #pragma unroll
            for (int jf = 0; jf < 4; ++jf) {
                short8 bf = *(const short8*)&Kl[jf*16 + c][ks*32 + 8*g];
                acc_s[jf] = __builtin_amdgcn_mfma_f32_16x16x32_bf16(qa[ks], bf, acc_s[jf], 0,0,0);
            }
        f32x4 acc_b[5] = {};
        #pragma unroll
        for (int ks = 0; ks < 2; ++ks)
            #pragma unroll
            for (int fi = 0; fi < 5; ++fi) {
                short8 bf = *(const short8*)&Pl[(3-w+fi)*16 + c][ks*32 + 8*g];
                acc_b[fi] = __builtin_amdgcn_mfma_f32_16x16x32_bf16(qv[ks], bf, acc_b[fi], 0,0,0);
            }
        #pragma unroll
        for (int fi = 0; fi < 5; ++fi)
            #pragma unroll
            for (int r = 0; r < 4; ++r)
                BDs[w][4*g + r][16*fi + c] = acc_b[fi][r];
        __syncthreads();

        float rmax[4];
        #pragma unroll
        for (int r = 0; r < 4; ++r) rmax[r] = -1e30f;
        #pragma unroll
        for (int jf = 0; jf < 4; ++jf)
            #pragma unroll
            for (int r = 0; r < 4; ++r) {
                int row = 4*g + r;
                float s = acc_s[jf][r] + BDs[w][row][15 - row + 16*jf + c];
                acc_s[jf][r] = s;
                rmax[r] = fmaxf(rmax[r], s);
            }
        #pragma unroll
        for (int r = 0; r < 4; ++r)
            #pragma unroll
            for (int msk = 1; msk < 16; msk <<= 1)
                rmax[r] = fmaxf(rmax[r], __shfl_xor(rmax[r], msk));
        float fs[4], rsum[4];
        #pragma unroll
        for (int r = 0; r < 4; ++r) {
            float mn = fmaxf(m_run[r], rmax[r]);
            fs[r] = __expf(m_run[r] - mn);
            m_run[r] = mn;
            rsum[r] = 0.f;
        }
        #pragma unroll
        for (int jf = 0; jf < 4; ++jf)
            #pragma unroll
            for (int r = 0; r < 4; ++r) {
                float p = __expf(acc_s[jf][r] - m_run[r]);
                rsum[r] += p;
                Pa[w][4*g + r][16*jf + c] = f2bf(p);
            }
        #pragma unroll
        for (int r = 0; r < 4; ++r) {
            #pragma unroll
            for (int msk = 1; msk < 16; msk <<= 1)
                rsum[r] += __shfl_xor(rsum[r], msk);
            l_run[r] = l_run[r]*fs[r] + rsum[r];
        }
        #pragma unroll
        for (int df = 0; df < 4; ++df)
            #pragma unroll
            for (int r = 0; r < 4; ++r)
                acc_o[df][r] *= fs[r];
        __syncthreads();

        #pragma unroll
        for (int ks = 0; ks < 2; ++ks) {
            short8 pa = *(const short8*)&Pa[w][c][ks*32 + 8*g];
            #pragma unroll
            for (int df = 0; df < 4; ++df) {
                short8 bv = *(const short8*)&Vl[df*16 + c][ks*32 + 8*g];
                acc_o[df] = __builtin_amdgcn_mfma_f32_16x16x32_bf16(pa, bv, acc_o[df], 0,0,0);
            }
        }
    }

    #pragma unroll
    for (int df = 0; df < 4; ++df)
        #pragma unroll
        for (int r = 0; r < 4; ++r) {
            int t = t0 + 16*w + 4*g + r;
            O[((size_t)t*BB + b)*CH + h*HDIM + 16*df + c] = f2bf(acc_o[df][r] / l_run[r]);
        }
}

// ---------------- depthwise conv + BN + swish, write token-major bf16 ----------------
__global__ __launch_bounds__(256)
void dwconv_kernel(const float* __restrict__ In,
                   const float* __restrict__ W,
                   const float* __restrict__ CB,
                   const float* __restrict__ BNG, const float* __restrict__ BNB,
                   const float* __restrict__ BNM, const float* __restrict__ BNV,
                   short* __restrict__ Out)
{
    int c = blockIdx.x, b = blockIdx.y;
    __shared__ float row[TT + KW - 1];
    __shared__ float wv[KW];
    int tid = threadIdx.x;
    const float* base = In + ((size_t)b*CH + c)*TT;
    for (int i = tid; i < TT + KW - 1; i += 256) {
        int tp = i - (KW-1)/2;
        row[i] = (tp >= 0 && tp < TT) ? base[tp] : 0.f;
    }
    if (tid < KW) wv[tid] = W[c*KW + tid];
    float bias = CB[c];
    float scl  = rsqrtf(BNV[c] + EPSV) * BNG[c];
    float sh   = BNB[c];
    float mn   = BNM[c];
    __syncthreads();
    #pragma unroll
    for (int r = 0; r < 4; ++r) {
        int t = tid + 256*r;
        float acc = 0.f;
        #pragma unroll
        for (int k = 0; k < KW; ++k) acc += row[t + k] * wv[k];
        float v = (acc + bias - mn) * scl + sh;
        v = v / (1.f + __expf(-v));
        Out[((size_t)t*BB + b)*CH + c] = f2bf(v);
    }
}

extern "C" void kernel_launch(void* const* d_in, const int* in_sizes, int n_in,
                              void* d_out, int out_size, void* d_ws, size_t ws_size,
                              hipStream_t stream)
{
    const float* x_in    = (const float*)d_in[0];
    const float* pos_emb = (const float*)d_in[1];
    const float* ffm_w1  = (const float*)d_in[2];
    const float* ffm_b1  = (const float*)d_in[3];
    const float* ffm_w2  = (const float*)d_in[4];
    const float* ffm_b2  = (const float*)d_in[5];
    const float* ff_w1   = (const float*)d_in[6];
    const float* ff_b1   = (const float*)d_in[7];
    const float* ff_w2   = (const float*)d_in[8];
    const float* ff_b2   = (const float*)d_in[9];
    const float* in_w    = (const float*)d_in[10];
    const float* in_b    = (const float*)d_in[11];
    const float* out_w   = (const float*)d_in[12];
    const float* out_b   = (const float*)d_in[13];
    const float* pos_w   = (const float*)d_in[14];
    const float* bias_u  = (const float*)d_in[15];
    const float* bias_v  = (const float*)d_in[16];
    const float* pw1_w   = (const float*)d_in[17];
    const float* pw1_b   = (const float*)d_in[18];
    const float* dw_w    = (const float*)d_in[19];
    const float* dw_b    = (const float*)d_in[20];
    const float* bn_g    = (const float*)d_in[21];
    const float* bn_b    = (const float*)d_in[22];
    const float* bn_m    = (const float*)d_in[23];
    const float* bn_v    = (const float*)d_in[24];
    const float* pw2_w   = (const float*)d_in[25];
    const float* pw2_b   = (const float*)d_in[26];
    const float* ln_g    = (const float*)d_in[27];
    const float* ln_b    = (const float*)d_in[28];

    char* wp = (char*)d_ws;
    auto alloc = [&](size_t bytes) -> void* {
        void* p = wp; wp += (bytes + 255) & ~(size_t)255; return p;
    };
    float* xbuf = (float*)alloc((size_t)TB*CH*4);
    short* ybf  = (short*)alloc((size_t)TB*CH*2);
    short* hff  = (short*)alloc((size_t)TB*DFFN*2);
    float* c2   = (float*)alloc((size_t)BB*CH*TT*4);
    short* abf  = (short*)alloc((size_t)TB*CH*2);
    short* qub  = (short*)alloc((size_t)BB*NH*TT*HDIM*2);
    short* qvb  = (short*)alloc((size_t)BB*NH*TT*HDIM*2);
    short* kb   = (short*)alloc((size_t)BB*NH*TT*HDIM*2);
    short* vtb  = (short*)alloc((size_t)BB*NH*TT*HDIM*2);
    short* pbb  = (short*)alloc((size_t)NH*2048*HDIM*2);
    short* wbf[NL][9];
    int    wn[9] = { DFFN*CH, CH*DFFN, DFFN*CH, CH*DFFN, 3*CH*CH, CH*CH, CH*CH, 2*CH*CH, CH*CH };
    const float* wsrc[NL][9];
    for (int i = 0; i < NL; ++i) {
        const float* srcs[9] = {
            ffm_w1 + (size_t)i*DFFN*CH, ffm_w2 + (size_t)i*CH*DFFN,
            ff_w1  + (size_t)i*DFFN*CH, ff_w2  + (size_t)i*CH*DFFN,
            in_w   + (size_t)i*3*CH*CH, out_w  + (size_t)i*CH*CH,
            pos_w  + (size_t)i*CH*CH,   pw1_w  + (size_t)i*2*CH*CH,
            pw2_w  + (size_t)i*CH*CH };
        for (int j = 0; j < 9; ++j) {
            wsrc[i][j] = srcs[j];
            wbf[i][j]  = (short*)alloc((size_t)wn[j]*2);
        }
    }
    short* posbf = (short*)alloc((size_t)(2*TT-1)*CH*2);
    if ((size_t)(wp - (char*)d_ws) > ws_size) return;

    // zero pbb once: pos epilogue writes rows 0..2046 each layer; row 2047 stays 0
    hipMemsetAsync(pbb, 0, (size_t)NH*2048*HDIM*2, stream);

    CvtArgs ca;
    int nseg = 0, maxn = 0;
    for (int i = 0; i < NL; ++i)
        for (int j = 0; j < 9; ++j) {
            ca.seg[nseg++] = { wsrc[i][j], wbf[i][j], wn[j], (j == 7) ? 1 : 0 };
            if (wn[j] > maxn) maxn = wn[j];
        }
    ca.seg[nseg++] = { pos_emb, posbf, (2*TT-1)*CH, 0 };
    if ((2*TT-1)*CH > maxn) maxn = (2*TT-1)*CH;
    cvt_kernel<<<dim3((maxn/8 + 255)/256, nseg), 256, 0, stream>>>(ca);

    const float* cur = x_in;
    for (int i = 0; i < NL; ++i) {
        const float* lng = ln_g + (size_t)i*5*CH;
        const float* lnb = ln_b + (size_t)i*5*CH;

        // ---- macaron FFN ----
        ln_kernel<1><<<TB/4, 256, 0, stream>>>(cur, lng + 0*CH, lnb + 0*CH, ybf);
        gemm_bf<1,1><<<dim3(DFFN/64, TB/64), 256, 0, stream>>>(
            ybf, CH, 0, wbf[i][0], CH, 0, hff, DFFN, 1, 0,
            nullptr, ffm_b1 + (size_t)i*DFFN, nullptr, 1.f, TB, DFFN, CH,
            nullptr,nullptr,nullptr,nullptr,nullptr,nullptr);
        gemm_bf<0,0><<<dim3(CH/64, TB/64), 256, 0, stream>>>(
            hff, DFFN, 0, wbf[i][1], DFFN, 0, xbuf, CH, 1, 0,
            nullptr, ffm_b2 + (size_t)i*CH, cur, 0.5f, TB, CH, DFFN,
            nullptr,nullptr,nullptr,nullptr,nullptr,nullptr);
        cur = xbuf;

        // ---- rel-pos attention ----
        ln_kernel<1><<<TB/4, 256, 0, stream>>>(cur, lng + 1*CH, lnb + 1*CH, ybf);
        gemm_bf<3,1><<<dim3(3*CH/64, TB/64), 256, 0, stream>>>(
            ybf, CH, 0, wbf[i][4], CH, 0, nullptr, 0, 0, 0,
            nullptr, in_b + (size_t)i*3*CH, nullptr, 1.f, TB, 3*CH, CH,
            qub, qvb, kb, vtb,
            bias_u + (size_t)i*NH*HDIM, bias_v + (size_t)i*NH*HDIM);
        gemm_bf<4,1><<<dim3(CH/64, (2*TT-1+63)/64), 256, 0, stream>>>(
            posbf, CH, 0, wbf[i][6], CH, 0, nullptr, 0, 0, 0,
            nullptr, nullptr, nullptr, 1.f, 2*TT-1, CH, CH,
            pbb, nullptr, nullptr, nullptr, nullptr, nullptr);
        attn_mfma_kernel<<<dim3(TT/64, NH, BB), 256, 0, stream>>>(
            qub, qvb, kb, vtb, pbb, abf);
        gemm_bf<0,0><<<dim3(CH/64, TB/64), 256, 0, stream>>>(
            abf, CH, 0, wbf[i][5], CH, 0, xbuf, CH, 1, 0,
            nullptr, out_b + (size_t)i*CH, cur, 1.f, TB, CH, CH,
            nullptr,nullptr,nullptr,nullptr,nullptr,nullptr);

        // ---- conv module ----
        ln_kernel<1><<<TB/4, 256, 0, stream>>>(cur, lng + 2*CH, lnb + 2*CH, ybf);
        gemm_bf<2,0><<<dim3(TT/64, (2*CH)/64, BB), 256, 0, stream>>>(
            wbf[i][7], CH, 0, ybf, BB*CH, CH, c2, TT, 1, (long)CH*TT,
            pw1_b + (size_t)i*2*CH, nullptr, nullptr, 1.f, 2*CH, TT, CH,
            nullptr,nullptr,nullptr,nullptr,nullptr,nullptr);
        dwconv_kernel<<<dim3(CH, BB), 256, 0, stream>>>(
            c2, dw_w + (size_t)i*CH*KW, dw_b + (size_t)i*CH,
            bn_g + (size_t)i*CH, bn_b + (size_t)i*CH,
            bn_m + (size_t)i*CH, bn_v + (size_t)i*CH, abf);
        gemm_bf<0,0><<<dim3(CH/64, TB/64), 256, 0, stream>>>(
            abf, CH, 0, wbf[i][8], CH, 0, xbuf, CH, 1, 0,
            nullptr, pw2_b + (size_t)i*CH, cur, 1.f, TB, CH, CH,
            nullptr,nullptr,nullptr,nullptr,nullptr,nullptr);

        // ---- second FFN ----
        ln_kernel<1><<<TB/4, 256, 0, stream>>>(cur, lng + 3*CH, lnb + 3*CH, ybf);
        gemm_bf<1,1><<<dim3(DFFN/64, TB/64), 256, 0, stream>>>(
            ybf, CH, 0, wbf[i][2], CH, 0, hff, DFFN, 1, 0,
            nullptr, ff_b1 + (size_t)i*DFFN, nullptr, 1.f, TB, DFFN, CH,
            nullptr,nullptr,nullptr,nullptr,nullptr,nullptr);
        gemm_bf<0,0><<<dim3(CH/64, TB/64), 256, 0, stream>>>(
            hff, DFFN, 0, wbf[i][3], DFFN, 0, xbuf, CH, 1, 0,
            nullptr, ff_b2 + (size_t)i*CH, cur, 0.5f, TB, CH, DFFN,
            nullptr,nullptr,nullptr,nullptr,nullptr,nullptr);

        // ---- final LN ----
        if (i == NL-1)
            ln_kernel<0><<<TB/4, 256, 0, stream>>>(xbuf, lng + 4*CH, lnb + 4*CH, (float*)d_out);
        else
            ln_kernel<0><<<TB/4, 256, 0, stream>>>(xbuf, lng + 4*CH, lnb + 4*CH, xbuf);
        cur = xbuf;
    }
}

// Round 6
// 449.056 us; speedup vs baseline: 13.8640x; 1.2362x over previous
//
#include <hip/hip_runtime.h>
#include <math.h>

#define TT 1024
#define BB 4
#define CH 256
#define NH 4
#define HDIM 64
#define DFFN 1024
#define KW 31
#define NL 2
#define TB (TT*BB)
#define EPSV 1e-5f

typedef __attribute__((ext_vector_type(8))) short short8;
typedef __attribute__((ext_vector_type(4))) short short4v;
typedef __attribute__((ext_vector_type(4))) float f32x4;

__device__ __forceinline__ short f2bf(float f){
    union { float f; unsigned u; } x; x.f = f;
    unsigned r = x.u + 0x7fffu + ((x.u >> 16) & 1u);
    return (short)(r >> 16);
}

// ---------------- batched f32 -> bf16 convert (mode 1 = pw1 row-interleave) ----------------
struct CvtSeg { const float* src; short* dst; int n; int mode; };
struct CvtArgs { CvtSeg seg[20]; };

__global__ __launch_bounds__(256)
void cvt_kernel(CvtArgs args)
{
    CvtSeg s = args.seg[blockIdx.y];
    int i = (blockIdx.x*256 + threadIdx.x)*8;
    if (i >= s.n) return;
    float4 a = *(const float4*)(s.src + i);
    float4 b = *(const float4*)(s.src + i + 4);
    short8 o;
    o[0]=f2bf(a.x); o[1]=f2bf(a.y); o[2]=f2bf(a.z); o[3]=f2bf(a.w);
    o[4]=f2bf(b.x); o[5]=f2bf(b.y); o[6]=f2bf(b.z); o[7]=f2bf(b.w);
    int di = i;
    if (s.mode == 1) {            // pw1 (512x256): src row c -> dst row (c<256 ? 2c : 2(c-256)+1)
        int c = i >> 8, k = i & 255;
        int dr = (c < 256) ? 2*c : 2*(c-256)+1;
        di = dr*256 + k;
    }
    *(short8*)(s.dst + di) = o;
}

// ---------------- LayerNorm: 4 rows/block, float4 per lane, wave reduce ----------------
template<int OUTBF>
__global__ __launch_bounds__(256)
void ln_kernel(const float* __restrict__ X, const float* __restrict__ G,
               const float* __restrict__ Bt, void* __restrict__ Y)
{
    int row  = blockIdx.x*4 + (threadIdx.x >> 6);
    int lane = threadIdx.x & 63;
    float4 v = ((const float4*)X)[(size_t)row*64 + lane];
    float s  = v.x + v.y + v.z + v.w;
    float s2 = v.x*v.x + v.y*v.y + v.z*v.z + v.w*v.w;
    #pragma unroll
    for (int off = 32; off >= 1; off >>= 1) {
        s  += __shfl_xor(s, off);
        s2 += __shfl_xor(s2, off);
    }
    float mean = s * (1.0f/CH);
    float var  = s2 * (1.0f/CH) - mean*mean;
    float inv  = rsqrtf(var + EPSV);
    float4 g4 = ((const float4*)G)[lane];
    float4 b4 = ((const float4*)Bt)[lane];
    float o0 = (v.x-mean)*inv*g4.x + b4.x;
    float o1 = (v.y-mean)*inv*g4.y + b4.y;
    float o2 = (v.z-mean)*inv*g4.z + b4.z;
    float o3 = (v.w-mean)*inv*g4.w + b4.w;
    if (OUTBF) {
        short4v o; o[0]=f2bf(o0); o[1]=f2bf(o1); o[2]=f2bf(o2); o[3]=f2bf(o3);
        *(short4v*)((short*)Y + (size_t)row*CH + lane*4) = o;
    } else {
        float4 o = {o0,o1,o2,o3};
        ((float4*)Y)[(size_t)row*64 + lane] = o;
    }
}

// ---------------- bf16 MFMA GEMM, 64x64 tile, dbuf LDS + reg prefetch ----------------
// ACT: 0 none, 1 swish, 2 GLU(pw1, interleaved weights), 3 QKV-prep, 4 POS-scatter
template<int ACT, int OUTBF>
__global__ __launch_bounds__(256)
void gemm_bf(const short* __restrict__ A, int lda, long sA,
             const short* __restrict__ Bm, int ldb, long sB,
             void* __restrict__ Cv, long ldcm, long ldcn, long sC,
             const float* __restrict__ biasM, const float* __restrict__ biasN,
             const float* __restrict__ Rm, float scale,
             int M, int N, int Kd,
             short* __restrict__ x1, short* __restrict__ x2,
             short* __restrict__ x3, short* __restrict__ x4,
             const float* __restrict__ f1, const float* __restrict__ f2)
{
    __shared__ short As[2][64][72];
    __shared__ short Bs[2][64][72];
    const int bz = blockIdx.z;
    A  += (long)bz * sA;
    Bm += (long)bz * sB;
    const int m0 = blockIdx.y * 64;
    const int n0 = blockIdx.x * 64;
    const int tid = threadIdx.x;
    const int w = tid >> 6, lane = tid & 63;
    const int g = lane >> 4, c = lane & 15;
    const int wr = w >> 1, wc = w & 1;
    const int srow = tid >> 3, scol = (tid & 7) * 8;

    // per-thread source pointers (row-clamped; epilogue bounds-checks writes)
    const short *Ap0, *Ap1, *Bp0, *Bp1;
    {
        int gm0 = m0 + srow;      if (gm0 >= M) gm0 = M - 1;
        int gm1 = m0 + srow + 32; if (gm1 >= M) gm1 = M - 1;
        int gn0 = n0 + srow;      if (gn0 >= N) gn0 = N - 1;
        int gn1 = n0 + srow + 32; if (gn1 >= N) gn1 = N - 1;
        Ap0 = A  + (long)gm0*lda + scol;
        Ap1 = A  + (long)gm1*lda + scol;
        Bp0 = Bm + (long)gn0*ldb + scol;
        Bp1 = Bm + (long)gn1*ldb + scol;
    }
    short8 pa0 = *(const short8*)(Ap0);
    short8 pa1 = *(const short8*)(Ap1);
    short8 pb0 = *(const short8*)(Bp0);
    short8 pb1 = *(const short8*)(Bp1);

    f32x4 acc[2][2] = {};
    int buf = 0;
    for (int kt = 0; kt < Kd; kt += 64) {
        *(short8*)&As[buf][srow   ][scol] = pa0;
        *(short8*)&As[buf][srow+32][scol] = pa1;
        *(short8*)&Bs[buf][srow   ][scol] = pb0;
        *(short8*)&Bs[buf][srow+32][scol] = pb1;
        __syncthreads();
        if (kt + 64 < Kd) {     // issue next-tile loads; latency hides under MFMAs
            pa0 = *(const short8*)(Ap0 + kt + 64);
            pa1 = *(const short8*)(Ap1 + kt + 64);
            pb0 = *(const short8*)(Bp0 + kt + 64);
            pb1 = *(const short8*)(Bp1 + kt + 64);
        }
        #pragma unroll
        for (int ks = 0; ks < 2; ++ks) {
            short8 af[2], bfr[2];
            #pragma unroll
            for (int i = 0; i < 2; ++i) af[i]  = *(const short8*)&As[buf][wr*32 + i*16 + c][ks*32 + 8*g];
            #pragma unroll
            for (int j = 0; j < 2; ++j) bfr[j] = *(const short8*)&Bs[buf][wc*32 + j*16 + c][ks*32 + 8*g];
            #pragma unroll
            for (int i = 0; i < 2; ++i)
                #pragma unroll
                for (int j = 0; j < 2; ++j)
                    acc[i][j] = __builtin_amdgcn_mfma_f32_16x16x32_bf16(af[i], bfr[j], acc[i][j], 0,0,0);
        }
        buf ^= 1;
        // single barrier per K-step: next write goes to buf^1, which all waves
        // finished reading one iteration ago (protected by this iteration's barrier)
    }

    if (ACT == 3) {
        // QKV prep: A=ln(x) tokens (m = t*BB+b), B=in_w rows (n in 0..767)
        const int region = n0 >> 8;
        #pragma unroll
        for (int i = 0; i < 2; ++i)
            #pragma unroll
            for (int r = 0; r < 4; ++r) {
                int m = m0 + wr*32 + i*16 + 4*g + r;
                int t = m >> 2, b = m & 3;
                #pragma unroll
                for (int j = 0; j < 2; ++j) {
                    int n = n0 + wc*32 + j*16 + c;
                    float v = acc[i][j][r] + biasN[n];
                    int h = (n >> 6) & 3, d = n & 63;
                    int bh = b*NH + h;
                    if (region == 0) {
                        float q = v * 0.125f;
                        size_t di = ((size_t)bh*TT + t)*HDIM + d;
                        x1[di] = f2bf(q + f1[h*HDIM + d]);
                        x2[di] = f2bf(q + f2[h*HDIM + d]);
                    } else if (region == 1) {
                        x3[((size_t)bh*TT + t)*HDIM + d] = f2bf(v);
                    } else {
                        x4[((size_t)bh*HDIM + d)*TT + t] = f2bf(v);
                    }
                }
            }
        return;
    }
    if (ACT == 4) {
        // POS scatter: m = pos row (0..2046), n -> (h,d); dst (h,2048,64)
        #pragma unroll
        for (int i = 0; i < 2; ++i)
            #pragma unroll
            for (int r = 0; r < 4; ++r) {
                int m = m0 + wr*32 + i*16 + 4*g + r;
                if (m >= M) continue;
                #pragma unroll
                for (int j = 0; j < 2; ++j) {
                    int n = n0 + wc*32 + j*16 + c;
                    int h = n >> 6, d = n & 63;
                    x1[((size_t)h*2048 + m)*HDIM + d] = f2bf(acc[i][j][r]);
                }
            }
        return;
    }
    if (ACT == 2) {
        // GLU: interleaved rows (even=a, odd=g); out channel m>>1; C shape (B,CH,TT) fp32
        float* Cf = (float*)Cv + (long)bz*sC;
        #pragma unroll
        for (int i = 0; i < 2; ++i)
            #pragma unroll
            for (int rp = 0; rp < 2; ++rp) {
                int ma = m0 + wr*32 + i*16 + 4*g + 2*rp;
                float va = acc[i][0][2*rp]   + biasM[ma>>1];
                float vg = acc[i][0][2*rp+1] + biasM[(ma>>1)+CH];
                float vb = acc[i][1][2*rp]   + biasM[ma>>1];
                float hg = acc[i][1][2*rp+1] + biasM[(ma>>1)+CH];
                #pragma unroll
                for (int j = 0; j < 2; ++j) {
                    int n = n0 + wc*32 + j*16 + c;
                    float a = j ? vb : va;
                    float gg = j ? hg : vg;
                    Cf[(long)(ma>>1)*ldcm + n] = a / (1.f + __expf(-gg));
                }
            }
        return;
    }

    #pragma unroll
    for (int i = 0; i < 2; ++i) {
        #pragma unroll
        for (int r = 0; r < 4; ++r) {
            int m = m0 + wr*32 + i*16 + 4*g + r;
            if (m >= M) continue;
            float bm = biasM ? biasM[m] : 0.f;
            #pragma unroll
            for (int j = 0; j < 2; ++j) {
                int n = n0 + wc*32 + j*16 + c;
                if (n >= N) continue;
                float v = acc[i][j][r] + bm + (biasN ? biasN[n] : 0.f);
                if (ACT == 1) v = v / (1.f + __expf(-v));
                v *= scale;
                long ci = (long)m*ldcm + (long)n*ldcn;
                if (OUTBF) {
                    ((short*)Cv)[(long)bz*sC + ci] = f2bf(v);
                } else {
                    float* Cf = (float*)Cv + (long)bz*sC;
                    if (Rm) v += (Rm + (long)bz*sC)[ci];
                    Cf[ci] = v;
                }
            }
        }
    }
}

// ---------------- MFMA flash attention with fused rel_shift (reg-prefetch pipeline) ----------------
__global__ __launch_bounds__(256)
void attn_mfma_kernel(const short* __restrict__ qub, const short* __restrict__ qvb,
                      const short* __restrict__ kb, const short* __restrict__ vtb,
                      const short* __restrict__ pbf, short* __restrict__ O)
{
    const int t0 = blockIdx.x * 64;
    const int h  = blockIdx.y, b = blockIdx.z;
    const int bh = b*NH + h;
    const int tid = threadIdx.x;
    const int w = tid >> 6, lane = tid & 63;
    const int g = lane >> 4, c = lane & 15;

    __shared__ short Kl[64][88];
    __shared__ short Vl[64][88];
    __shared__ short Pl[128][88];
    __shared__ float BDs[4][16][84];   // per-wave [w] strips
    __shared__ short Pa[4][16][88];    // per-wave [w] strips

    short8 qa[2], qv[2];
    {
        const short* qr = qub + ((size_t)bh*TT + t0 + 16*w + c)*HDIM;
        const short* vr = qvb + ((size_t)bh*TT + t0 + 16*w + c)*HDIM;
        qa[0] = *(const short8*)(qr + 8*g);
        qa[1] = *(const short8*)(qr + 32 + 8*g);
        qv[0] = *(const short8*)(vr + 8*g);
        qv[1] = *(const short8*)(vr + 32 + 8*g);
    }

    // per-thread staging addresses
    const short* ksrc = kb  + (size_t)bh*TT*HDIM + tid*8;                       // + j0*HDIM
    const short* vsrc = vtb + ((size_t)bh*HDIM + (tid>>3))*TT + (tid&7)*8;      // + j0 (rows tid>>3, tid>>3+32)
    const short* psrc = pbf + ((size_t)h*2048 + (960 - t0))*HDIM + tid*8;       // + j0*HDIM

    short8 rk0, rk1, rv0, rv1, rp0, rp1, rp2, rp3;
    {
        rk0 = *(const short8*)(ksrc);
        rk1 = *(const short8*)(ksrc + 2048);
        rv0 = *(const short8*)(vsrc);
        rv1 = *(const short8*)(vsrc + 32*TT);
        rp0 = *(const short8*)(psrc);
        rp1 = *(const short8*)(psrc + 2048);
        rp2 = *(const short8*)(psrc + 4096);
        rp3 = *(const short8*)(psrc + 6144);
    }

    f32x4 acc_o[4] = {};
    float m_run[4], l_run[4];
    #pragma unroll
    for (int r = 0; r < 4; ++r){ m_run[r] = -1e30f; l_run[r] = 0.f; }

    for (int jt = 0; jt < 16; ++jt) {
        // ---- write staged regs to LDS ----
        {
            int ci0 = tid, ci1 = tid + 256;
            *(short8*)&Kl[ci0>>3][(ci0&7)*8] = rk0;
            *(short8*)&Kl[ci1>>3][(ci1&7)*8] = rk1;
            *(short8*)&Vl[ci0>>3][(ci0&7)*8] = rv0;
            *(short8*)&Vl[ci1>>3][(ci1&7)*8] = rv1;
            *(short8*)&Pl[(ci0>>3)     ][(ci0&7)*8] = rp0;
            *(short8*)&Pl[(ci1>>3)     ][(ci1&7)*8] = rp1;
            *(short8*)&Pl[(ci0>>3) + 64][(ci0&7)*8] = rp2;
            *(short8*)&Pl[(ci1>>3) + 64][(ci1&7)*8] = rp3;
        }
        __syncthreads();
        // ---- issue next tile's loads (hide under compute) ----
        if (jt < 15) {
            int j0n = (jt+1)*64;
            rk0 = *(const short8*)(ksrc + (size_t)j0n*HDIM);
            rk1 = *(const short8*)(ksrc + (size_t)j0n*HDIM + 2048);
            rv0 = *(const short8*)(vsrc + j0n);
            rv1 = *(const short8*)(vsrc + j0n + 32*TT);
            rp0 = *(const short8*)(psrc + (size_t)j0n*HDIM);
            rp1 = *(const short8*)(psrc + (size_t)j0n*HDIM + 2048);
            rp2 = *(const short8*)(psrc + (size_t)j0n*HDIM + 4096);
            rp3 = *(const short8*)(psrc + (size_t)j0n*HDIM + 6144);
        }

        // ---- AC = qu . K^T ----
        f32x4 acc_s[4] = {};
        #pragma unroll
        for (int ks = 0; ks < 2; ++ks)
            #pragma unroll
            for (int jf = 0; jf < 4; ++jf) {
                short8 bf = *(const short8*)&Kl[jf*16 + c][ks*32 + 8*g];
                acc_s[jf] = __builtin_amdgcn_mfma_f32_16x16x32_bf16(qa[ks], bf, acc_s[jf], 0,0,0);
            }
        // ---- BD = qv . P^T (5 frags, shifted base 3-w) ----
        f32x4 acc_b[5] = {};
        #pragma unroll
        for (int ks = 0; ks < 2; ++ks)
            #pragma unroll
            for (int fi = 0; fi < 5; ++fi) {
                short8 bf = *(const short8*)&Pl[(3-w+fi)*16 + c][ks*32 + 8*g];
                acc_b[fi] = __builtin_amdgcn_mfma_f32_16x16x32_bf16(qv[ks], bf, acc_b[fi], 0,0,0);
            }
        #pragma unroll
        for (int fi = 0; fi < 5; ++fi)
            #pragma unroll
            for (int r = 0; r < 4; ++r)
                BDs[w][4*g + r][16*fi + c] = acc_b[fi][r];
        // BDs/Pa are per-wave strips: in-wave DS ordering (compiler lgkmcnt) suffices, no barrier

        // ---- combine (shifted BD) + online softmax ----
        float rmax[4];
        #pragma unroll
        for (int r = 0; r < 4; ++r) rmax[r] = -1e30f;
        #pragma unroll
        for (int jf = 0; jf < 4; ++jf)
            #pragma unroll
            for (int r = 0; r < 4; ++r) {
                int row = 4*g + r;
                float s = acc_s[jf][r] + BDs[w][row][15 - row + 16*jf + c];
                acc_s[jf][r] = s;
                rmax[r] = fmaxf(rmax[r], s);
            }
        #pragma unroll
        for (int r = 0; r < 4; ++r)
            #pragma unroll
            for (int msk = 1; msk < 16; msk <<= 1)
                rmax[r] = fmaxf(rmax[r], __shfl_xor(rmax[r], msk));
        float fs[4], rsum[4];
        #pragma unroll
        for (int r = 0; r < 4; ++r) {
            float mn = fmaxf(m_run[r], rmax[r]);
            fs[r] = __expf(m_run[r] - mn);
            m_run[r] = mn;
            rsum[r] = 0.f;
        }
        #pragma unroll
        for (int jf = 0; jf < 4; ++jf)
            #pragma unroll
            for (int r = 0; r < 4; ++r) {
                float p = __expf(acc_s[jf][r] - m_run[r]);
                rsum[r] += p;
                Pa[w][4*g + r][16*jf + c] = f2bf(p);
            }
        #pragma unroll
        for (int r = 0; r < 4; ++r) {
            #pragma unroll
            for (int msk = 1; msk < 16; msk <<= 1)
                rsum[r] += __shfl_xor(rsum[r], msk);
            l_run[r] = l_run[r]*fs[r] + rsum[r];
        }
        #pragma unroll
        for (int df = 0; df < 4; ++df)
            #pragma unroll
            for (int r = 0; r < 4; ++r)
                acc_o[df][r] *= fs[r];

        // ---- PV: O += P . V ----
        #pragma unroll
        for (int ks = 0; ks < 2; ++ks) {
            short8 pa = *(const short8*)&Pa[w][c][ks*32 + 8*g];
            #pragma unroll
            for (int df = 0; df < 4; ++df) {
                short8 bv = *(const short8*)&Vl[df*16 + c][ks*32 + 8*g];
                acc_o[df] = __builtin_amdgcn_mfma_f32_16x16x32_bf16(pa, bv, acc_o[df], 0,0,0);
            }
        }
        __syncthreads();   // all waves done reading Kl/Vl/Pl before next staging write
    }

    #pragma unroll
    for (int df = 0; df < 4; ++df)
        #pragma unroll
        for (int r = 0; r < 4; ++r) {
            int t = t0 + 16*w + 4*g + r;
            O[((size_t)t*BB + b)*CH + h*HDIM + 16*df + c] = f2bf(acc_o[df][r] / l_run[r]);
        }
}

// ---------------- depthwise conv + BN + swish, write token-major bf16 ----------------
__global__ __launch_bounds__(256)
void dwconv_kernel(const float* __restrict__ In,
                   const float* __restrict__ W,
                   const float* __restrict__ CB,
                   const float* __restrict__ BNG, const float* __restrict__ BNB,
                   const float* __restrict__ BNM, const float* __restrict__ BNV,
                   short* __restrict__ Out)
{
    int c = blockIdx.x, b = blockIdx.y;
    __shared__ float row[TT + KW - 1];
    __shared__ float wv[KW];
    int tid = threadIdx.x;
    const float* base = In + ((size_t)b*CH + c)*TT;
    for (int i = tid; i < TT + KW - 1; i += 256) {
        int tp = i - (KW-1)/2;
        row[i] = (tp >= 0 && tp < TT) ? base[tp] : 0.f;
    }
    if (tid < KW) wv[tid] = W[c*KW + tid];
    float bias = CB[c];
    float scl  = rsqrtf(BNV[c] + EPSV) * BNG[c];
    float sh   = BNB[c];
    float mn   = BNM[c];
    __syncthreads();
    #pragma unroll
    for (int r = 0; r < 4; ++r) {
        int t = tid + 256*r;
        float acc = 0.f;
        #pragma unroll
        for (int k = 0; k < KW; ++k) acc += row[t + k] * wv[k];
        float v = (acc + bias - mn) * scl + sh;
        v = v / (1.f + __expf(-v));
        Out[((size_t)t*BB + b)*CH + c] = f2bf(v);
    }
}

extern "C" void kernel_launch(void* const* d_in, const int* in_sizes, int n_in,
                              void* d_out, int out_size, void* d_ws, size_t ws_size,
                              hipStream_t stream)
{
    const float* x_in    = (const float*)d_in[0];
    const float* pos_emb = (const float*)d_in[1];
    const float* ffm_w1  = (const float*)d_in[2];
    const float* ffm_b1  = (const float*)d_in[3];
    const float* ffm_w2  = (const float*)d_in[4];
    const float* ffm_b2  = (const float*)d_in[5];
    const float* ff_w1   = (const float*)d_in[6];
    const float* ff_b1   = (const float*)d_in[7];
    const float* ff_w2   = (const float*)d_in[8];
    const float* ff_b2   = (const float*)d_in[9];
    const float* in_w    = (const float*)d_in[10];
    const float* in_b    = (const float*)d_in[11];
    const float* out_w   = (const float*)d_in[12];
    const float* out_b   = (const float*)d_in[13];
    const float* pos_w   = (const float*)d_in[14];
    const float* bias_u  = (const float*)d_in[15];
    const float* bias_v  = (const float*)d_in[16];
    const float* pw1_w   = (const float*)d_in[17];
    const float* pw1_b   = (const float*)d_in[18];
    const float* dw_w    = (const float*)d_in[19];
    const float* dw_b    = (const float*)d_in[20];
    const float* bn_g    = (const float*)d_in[21];
    const float* bn_b    = (const float*)d_in[22];
    const float* bn_m    = (const float*)d_in[23];
    const float* bn_v    = (const float*)d_in[24];
    const float* pw2_w   = (const float*)d_in[25];
    const float* pw2_b   = (const float*)d_in[26];
    const float* ln_g    = (const float*)d_in[27];
    const float* ln_b    = (const float*)d_in[28];

    char* wp = (char*)d_ws;
    auto alloc = [&](size_t bytes) -> void* {
        void* p = wp; wp += (bytes + 255) & ~(size_t)255; return p;
    };
    float* xbuf = (float*)alloc((size_t)TB*CH*4);
    short* ybf  = (short*)alloc((size_t)TB*CH*2);
    short* hff  = (short*)alloc((size_t)TB*DFFN*2);
    float* c2   = (float*)alloc((size_t)BB*CH*TT*4);
    short* abf  = (short*)alloc((size_t)TB*CH*2);
    short* qub  = (short*)alloc((size_t)BB*NH*TT*HDIM*2);
    short* qvb  = (short*)alloc((size_t)BB*NH*TT*HDIM*2);
    short* kb   = (short*)alloc((size_t)BB*NH*TT*HDIM*2);
    short* vtb  = (short*)alloc((size_t)BB*NH*TT*HDIM*2);
    short* pbb  = (short*)alloc((size_t)NH*2048*HDIM*2);
    short* wbf[NL][9];
    int    wn[9] = { DFFN*CH, CH*DFFN, DFFN*CH, CH*DFFN, 3*CH*CH, CH*CH, CH*CH, 2*CH*CH, CH*CH };
    const float* wsrc[NL][9];
    for (int i = 0; i < NL; ++i) {
        const float* srcs[9] = {
            ffm_w1 + (size_t)i*DFFN*CH, ffm_w2 + (size_t)i*CH*DFFN,
            ff_w1  + (size_t)i*DFFN*CH, ff_w2  + (size_t)i*CH*DFFN,
            in_w   + (size_t)i*3*CH*CH, out_w  + (size_t)i*CH*CH,
            pos_w  + (size_t)i*CH*CH,   pw1_w  + (size_t)i*2*CH*CH,
            pw2_w  + (size_t)i*CH*CH };
        for (int j = 0; j < 9; ++j) {
            wsrc[i][j] = srcs[j];
            wbf[i][j]  = (short*)alloc((size_t)wn[j]*2);
        }
    }
    short* posbf = (short*)alloc((size_t)(2*TT-1)*CH*2);
    if ((size_t)(wp - (char*)d_ws) > ws_size) return;

    // zero pbb once per call: pos epilogue writes rows 0..2046; row 2047 stays 0
    hipMemsetAsync(pbb, 0, (size_t)NH*2048*HDIM*2, stream);

    CvtArgs ca;
    int nseg = 0, maxn = 0;
    for (int i = 0; i < NL; ++i)
        for (int j = 0; j < 9; ++j) {
            ca.seg[nseg++] = { wsrc[i][j], wbf[i][j], wn[j], (j == 7) ? 1 : 0 };
            if (wn[j] > maxn) maxn = wn[j];
        }
    ca.seg[nseg++] = { pos_emb, posbf, (2*TT-1)*CH, 0 };
    if ((2*TT-1)*CH > maxn) maxn = (2*TT-1)*CH;
    cvt_kernel<<<dim3((maxn/8 + 255)/256, nseg), 256, 0, stream>>>(ca);

    const float* cur = x_in;
    for (int i = 0; i < NL; ++i) {
        const float* lng = ln_g + (size_t)i*5*CH;
        const float* lnb = ln_b + (size_t)i*5*CH;

        // ---- macaron FFN ----
        ln_kernel<1><<<TB/4, 256, 0, stream>>>(cur, lng + 0*CH, lnb + 0*CH, ybf);
        gemm_bf<1,1><<<dim3(DFFN/64, TB/64), 256, 0, stream>>>(
            ybf, CH, 0, wbf[i][0], CH, 0, hff, DFFN, 1, 0,
            nullptr, ffm_b1 + (size_t)i*DFFN, nullptr, 1.f, TB, DFFN, CH,
            nullptr,nullptr,nullptr,nullptr,nullptr,nullptr);
        gemm_bf<0,0><<<dim3(CH/64, TB/64), 256, 0, stream>>>(
            hff, DFFN, 0, wbf[i][1], DFFN, 0, xbuf, CH, 1, 0,
            nullptr, ffm_b2 + (size_t)i*CH, cur, 0.5f, TB, CH, DFFN,
            nullptr,nullptr,nullptr,nullptr,nullptr,nullptr);
        cur = xbuf;

        // ---- rel-pos attention ----
        ln_kernel<1><<<TB/4, 256, 0, stream>>>(cur, lng + 1*CH, lnb + 1*CH, ybf);
        gemm_bf<3,1><<<dim3(3*CH/64, TB/64), 256, 0, stream>>>(
            ybf, CH, 0, wbf[i][4], CH, 0, nullptr, 0, 0, 0,
            nullptr, in_b + (size_t)i*3*CH, nullptr, 1.f, TB, 3*CH, CH,
            qub, qvb, kb, vtb,
            bias_u + (size_t)i*NH*HDIM, bias_v + (size_t)i*NH*HDIM);
        gemm_bf<4,1><<<dim3(CH/64, (2*TT-1+63)/64), 256, 0, stream>>>(
            posbf, CH, 0, wbf[i][6], CH, 0, nullptr, 0, 0, 0,
            nullptr, nullptr, nullptr, 1.f, 2*TT-1, CH, CH,
            pbb, nullptr, nullptr, nullptr, nullptr, nullptr);
        attn_mfma_kernel<<<dim3(TT/64, NH, BB), 256, 0, stream>>>(
            qub, qvb, kb, vtb, pbb, abf);
        gemm_bf<0,0><<<dim3(CH/64, TB/64), 256, 0, stream>>>(
            abf, CH, 0, wbf[i][5], CH, 0, xbuf, CH, 1, 0,
            nullptr, out_b + (size_t)i*CH, cur, 1.f, TB, CH, CH,
            nullptr,nullptr,nullptr,nullptr,nullptr,nullptr);

        // ---- conv module ----
        ln_kernel<1><<<TB/4, 256, 0, stream>>>(cur, lng + 2*CH, lnb + 2*CH, ybf);
        gemm_bf<2,0><<<dim3(TT/64, (2*CH)/64, BB), 256, 0, stream>>>(
            wbf[i][7], CH, 0, ybf, BB*CH, CH, c2, TT, 1, (long)CH*TT,
            pw1_b + (size_t)i*2*CH, nullptr, nullptr, 1.f, 2*CH, TT, CH,
            nullptr,nullptr,nullptr,nullptr,nullptr,nullptr);
        dwconv_kernel<<<dim3(CH, BB), 256, 0, stream>>>(
            c2, dw_w + (size_t)i*CH*KW, dw_b + (size_t)i*CH,
            bn_g + (size_t)i*CH, bn_b + (size_t)i*CH,
            bn_m + (size_t)i*CH, bn_v + (size_t)i*CH, abf);
        gemm_bf<0,0><<<dim3(CH/64, TB/64), 256, 0, stream>>>(
            abf, CH, 0, wbf[i][8], CH, 0, xbuf, CH, 1, 0,
            nullptr, pw2_b + (size_t)i*CH, cur, 1.f, TB, CH, CH,
            nullptr,nullptr,nullptr,nullptr,nullptr,nullptr);

        // ---- second FFN ----
        ln_kernel<1><<<TB/4, 256, 0, stream>>>(cur, lng + 3*CH, lnb + 3*CH, ybf);
        gemm_bf<1,1><<<dim3(DFFN/64, TB/64), 256, 0, stream>>>(
            ybf, CH, 0, wbf[i][2], CH, 0, hff, DFFN, 1, 0,
            nullptr, ff_b1 + (size_t)i*DFFN, nullptr, 1.f, TB, DFFN, CH,
            nullptr,nullptr,nullptr,nullptr,nullptr,nullptr);
        gemm_bf<0,0><<<dim3(CH/64, TB/64), 256, 0, stream>>>(
            hff, DFFN, 0, wbf[i][3], DFFN, 0, xbuf, CH, 1, 0,
            nullptr, ff_b2 + (size_t)i*CH, cur, 0.5f, TB, CH, DFFN,
            nullptr,nullptr,nullptr,nullptr,nullptr,nullptr);

        // ---- final LN ----
        if (i == NL-1)
            ln_kernel<0><<<TB/4, 256, 0, stream>>>(xbuf, lng + 4*CH, lnb + 4*CH, (float*)d_out);
        else
            ln_kernel<0><<<TB/4, 256, 0, stream>>>(xbuf, lng + 4*CH, lnb + 4*CH, xbuf);
        cur = xbuf;
    }
}